// Round 7
// baseline (476.711 us; speedup 1.0000x reference)
//
#include <hip/hip_runtime.h>
#include <hip/hip_bf16.h>
#include <math.h>

#define DINL __device__ __forceinline__

namespace {
constexpr int Bn = 8, Cn = 3, Hn = 512, Wn = 512;
constexpr int HW  = Hn * Wn;        // 262144
constexpr int CHW = Cn * HW;        // 786432
constexpr float GEPS = 1e-5f;
constexpr float PIf  = 3.14159265358979323846f;

// workspace layout (bytes) — U half2, J/phi/dl fp16, y2 fp8 channel-last
constexpr size_t OFF_RED = 0;                                   // 128 floats
constexpr size_t OFF_PHI = 512;                                 // Bn*CHW ushort
constexpr size_t OFF_U   = OFF_PHI + (size_t)Bn * CHW * 2;      // Bn*CHW uint (half2)
constexpr size_t OFF_J   = OFF_U   + (size_t)Bn * CHW * 4;      // Bn*CHW ushort
constexpr size_t OFF_D   = OFF_J   + (size_t)Bn * CHW * 2;      // Bn*CHW ushort
constexpr size_t OFF_Y2  = OFF_D   + (size_t)Bn * CHW * 2;      // 8*32*HW fp8 (channel-last)
constexpr size_t OFF_W1B = OFF_Y2  + (size_t)Bn * 32 * HW;      // 3072 bf16
constexpr size_t OFF_W2F = OFF_W1B + 3072 * 2;                  // 9216 fp8 (mix conv2)
constexpr size_t OFF_WH1 = OFF_W2F + 9216;                      // 4608 bf16
constexpr size_t OFF_WP2 = OFF_WH1 + 4608 * 2;                  // 4608 fp8
constexpr size_t OFF_WZ2 = OFF_WP2 + 4608;                      // 4608 fp8
constexpr size_t OFF_PRM = OFF_WZ2 + 4608;                      // 160 f32
constexpr size_t OFF_PART= OFF_PRM + 160 * 4;                   // 81920 f32 partials
constexpr size_t OFF_TW  = OFF_PART + 81920 * 4;                // 512 float2 twiddles
// part float sub-offsets (in floats)
constexpr int PZ = 0;          // 24 groups (b*3+c) x 1024
constexpr int PG1 = 24576;     // 16 groups (b:sum, 8+b:ss) x 1024 (256 used; first 512 floats reused for x-stats)
constexpr int PG2 = 40960;     // 16 groups x 1024
constexpr int PD  = 57344;     // 24 groups (b*3+c) x 1024 (first 128 used)
}

typedef __bf16 bfx8 __attribute__((ext_vector_type(8)));
typedef float  fx4  __attribute__((ext_vector_type(4)));
typedef float  fx2  __attribute__((ext_vector_type(2)));

DINL float frcp(float a) { return __builtin_amdgcn_rcpf(a); }   // v_rcp_f32, 1 ULP
DINL float sigm(float a) { return frcp(1.f + __expf(-a)); }
DINL float siluf(float a) { return a * frcp(1.f + __expf(-a)); }
DINL float ftanh(float a) { return 1.f - 2.f * frcp(1.f + __expf(2.f * a)); }
DINL unsigned short f2bf(float f) {           // RNE float->bf16 bits
    unsigned u = __float_as_uint(f);
    return (unsigned short)((u + 0x7FFFu + ((u >> 16) & 1u)) >> 16);
}
DINL float bf2f(unsigned short h) {
    return __uint_as_float(((unsigned)h) << 16);
}
// truncating bf16 (LDS-internal MFMA operands only; 1 inst each)
DINL unsigned short t1(float a) { return (unsigned short)(__float_as_uint(a) >> 16); }
DINL unsigned t2(float a, float b) {
    return (__float_as_uint(a) >> 16) | (__float_as_uint(b) & 0xFFFF0000u);
}
// fp8 e4m3 (OCP) — saturating HW convert
DINL unsigned char f2f8(float v) {
    return (unsigned char)(__builtin_amdgcn_cvt_pk_fp8_f32(v, v, 0, false) & 0xFF);
}
DINL unsigned short pk8(float a, float b) {   // 2 fp8 in low 16 bits
    return (unsigned short)(__builtin_amdgcn_cvt_pk_fp8_f32(a, b, 0, false) & 0xFFFF);
}
DINL unsigned pk4f8(float a, float b, float c, float d) {  // 4 fp8 in a dword
    unsigned u = __builtin_amdgcn_cvt_pk_fp8_f32(a, b, 0, false);
    u = __builtin_amdgcn_cvt_pk_fp8_f32(c, d, u, true);
    return u;
}
template<int SEL>
DINL float f8f(unsigned u) { return __builtin_amdgcn_cvt_f32_fp8(u, SEL); }
// fp16 helpers
DINL unsigned pkh(float a, float b) {
    auto h = __builtin_amdgcn_cvt_pkrtz(a, b);   // __fp16 ext_vector(2)
    unsigned u; __builtin_memcpy(&u, &h, 4); return u;
}
DINL float2 uph(unsigned u) {
    _Float16 h[2]; __builtin_memcpy(h, &u, 4);
    return make_float2((float)h[0], (float)h[1]);
}
DINL unsigned short f2h(float a) {
    _Float16 h = (_Float16)a; unsigned short s; __builtin_memcpy(&s, &h, 2); return s;
}
DINL float h2f(unsigned short s) {
    _Float16 h; __builtin_memcpy(&h, &s, 2); return (float)h;
}

// LDS bank swizzle for the FFT float2 buffers: XOR bits 4-6 into bits 0-2.
DINL int SW(int e) { return e ^ ((e >> 4) & 7); }

DINL float blockReduceSum(float v) {   // blockDim.x == 256
    __shared__ float sm[4];
    int lane = threadIdx.x & 63, wid = threadIdx.x >> 6;
    #pragma unroll
    for (int o = 32; o > 0; o >>= 1) v += __shfl_down(v, o, 64);
    __syncthreads();
    if (lane == 0) sm[wid] = v;
    __syncthreads();
    if (wid == 0) {
        float r = (lane < 4) ? sm[lane] : 0.f;
        r += __shfl_down(r, 2, 64);
        r += __shfl_down(r, 1, 64);
        return r;                       // valid on thread 0
    }
    return 0.f;
}

DINL void blockReduceSum3(float& a, float& b, float& c) {   // valid on thread 0
    __shared__ float sm3[12];
    int lane = threadIdx.x & 63, wid = threadIdx.x >> 6;
    #pragma unroll
    for (int o = 32; o > 0; o >>= 1) {
        a += __shfl_down(a, o, 64);
        b += __shfl_down(b, o, 64);
        c += __shfl_down(c, o, 64);
    }
    __syncthreads();
    if (lane == 0) { sm3[wid] = a; sm3[4 + wid] = b; sm3[8 + wid] = c; }
    __syncthreads();
    if (threadIdx.x == 0) {
        a = sm3[0] + sm3[1] + sm3[2] + sm3[3];
        b = sm3[4] + sm3[5] + sm3[6] + sm3[7];
        c = sm3[8] + sm3[9] + sm3[10] + sm3[11];
    }
}

// merged: weight repack (0..35) + twiddle build (36) + x-stat partials (37..292)
// w1bf has the d5 channel FOLDED: w'_c = w_c - L_c*w_4 (c<3), w'_3 = w_3 + w_4.
__global__ __launch_bounds__(256) void k_init(
    const float* __restrict__ w1, const float* __restrict__ w2,
    const float* __restrict__ phw1, const float* __restrict__ zw1,
    const float* __restrict__ phw2, const float* __restrict__ zw2,
    const float* __restrict__ g2g, const float* __restrict__ g2b,
    const float* __restrict__ w3,
    unsigned short* __restrict__ w1bf, unsigned char* __restrict__ w2f8,
    unsigned short* __restrict__ wh1, unsigned char* __restrict__ wp2,
    unsigned char* __restrict__ wz2, float* __restrict__ prm,
    float2* __restrict__ gtw,
    const float* __restrict__ x, float* __restrict__ part)
{
    if (blockIdx.x < 36) {
        int i = blockIdx.x * 256 + threadIdx.x;     // 0..9215
        if (i < 3072) {
            int o = i / 96, k = i - o * 96;
            int ky = k >> 5, r = k & 31, kx = r >> 3, c = r & 7;
            float v = 0.f;
            if (kx < 3 && c < 4) {
                float base = w1[o * 45 + c * 9 + ky * 3 + kx];
                float w4   = w1[o * 45 + 4 * 9 + ky * 3 + kx];
                v = (c == 3) ? base + w4
                  : base - ((c == 0) ? 0.299f : (c == 1) ? 0.587f : 0.114f) * w4;
            }
            w1bf[i] = f2bf(v);
        }
        if (i < 9216) {
            int tap = i >> 10, rr = i & 1023, o = rr >> 5, ci = rr & 31;
            w2f8[i] = f2f8(w2[o * 288 + ci * 9 + tap]);
        }
        if (i < 4608) {
            int o = i / 96, k = i - o * 96;
            int ky = k >> 5, r = k & 31, kx = r >> 3, c = r & 7;
            float v = 0.f;
            if (kx < 3 && c < 3)
                v = (o < 16) ? phw1[o * 27 + c * 9 + ky * 3 + kx]
                             : zw1[(o - 16) * 27 + c * 9 + ky * 3 + kx];
            wh1[i] = f2bf(v);
        }
        if (i < 4608) {
            int tap = i / 512, rr = i - tap * 512, n = rr >> 5, k = rr & 31;
            float vp = (n < 3 && k < 16) ? phw2[n * 144 + k * 9 + tap] : 0.f;
            float vz = (n < 3) ? zw2[n * 288 + k * 9 + tap] : 0.f;
            wp2[i] = f2f8(vp);
            wz2[i] = f2f8(vz);
        }
        if (i < 160) {      // natural channel order (y2 byte j = channel j after conv2 swap)
            if (i < 32) {
                prm[i] = g2g[i];
            } else if (i < 64) {
                prm[i] = g2b[i - 32];
            } else {
                int j = (i - 64) & 31, c = (i - 64) >> 5;
                prm[i] = w3[c * 32 + j];
            }
        }
        return;
    }
    if (blockIdx.x == 36) {   // global twiddle table
        for (int i = threadIdx.x; i < 512; i += 256) {
            float s, c; __sincosf(-2.f * PIf * (float)i * (1.f / 512.f), &s, &c);
            gtw[i] = make_float2(c, s);
        }
        return;
    }
    const int bid = blockIdx.x - 37;
    const int b = bid >> 5, blk = bid & 31;
    const float4* xv = (const float4*)(x + (size_t)b * CHW + (size_t)blk * (CHW / 32));
    float s = 0.f, ss = 0.f;
    for (int i = threadIdx.x; i < (CHW / 32) / 4; i += 256) {
        float4 v = xv[i];
        s  += v.x + v.y + v.z + v.w;
        ss += v.x * v.x + v.y * v.y + v.z * v.z + v.w * v.w;
    }
    float rs = blockReduceSum(s);
    float rss = blockReduceSum(ss);
    if (threadIdx.x == 0) {
        part[PG1 + b * 64 + blk] = rs;
        part[PG1 + b * 64 + 32 + blk] = rss;
    }
}

// ---------------- fused heads (MFMA): xn -> [ph16 | z32] hidden(fp8) -> phi + z partials ----------------
__global__ __launch_bounds__(256) void k_heads(
    const float* __restrict__ x,
    const float* __restrict__ ng, const float* __restrict__ nb,
    const unsigned short* __restrict__ wh1,
    const float* __restrict__ phb1, const float* __restrict__ zb1,
    const unsigned char* __restrict__ wp2, const unsigned char* __restrict__ wz2,
    const float* __restrict__ phb2, const float* __restrict__ zb2,
    unsigned short* __restrict__ phi, float* __restrict__ part)
{
    const int tx0 = blockIdx.x * 16, ty0 = blockIdx.y * 16, b = blockIdx.z;
    const int local = blockIdx.y * 32 + blockIdx.x;
    const bool edge = (blockIdx.x == 0) || (blockIdx.x == 31) ||
                      (blockIdx.y == 0) || (blockIdx.y == 31);
    __shared__ unsigned short mt8[20 * 21 * 8];
    __shared__ __attribute__((aligned(16))) unsigned char ht8[324 * 48];  // fp8 hidden; reused as phs/zs
    __shared__ float xst[2];
    const int t = threadIdx.x;
    // folded x-stats reduce (32+32 partials from k_init)
    {
        const float* px = part + PG1 + (size_t)b * 64;
        float sv  = (t < 32) ? px[t] : 0.f;
        float ssv = (t >= 32 && t < 64) ? px[t] : 0.f;
        float r0 = blockReduceSum(sv);
        float r1 = blockReduceSum(ssv);
        if (t == 0) { xst[0] = r0; xst[1] = r1; }
        __syncthreads();
    }
    const float mu = xst[0] * (1.f / CHW);
    const float rsv = rsqrtf(xst[1] * (1.f / CHW) - mu * mu + GEPS);
    float sc[3], sh[3];
    #pragma unroll
    for (int c = 0; c < 3; ++c) { sc[c] = rsv * ng[c]; sh[c] = nb[c] - mu * rsv * ng[c]; }
    if (edge) {
        for (int e = t; e < 20 * 21; e += 256) {
            int yy = e / 21, xx = e - yy * 21;
            int gy = ty0 - 2 + yy, gx = tx0 - 2 + xx;
            float v0 = 0, v1 = 0, v2 = 0;
            if (xx < 20 && (unsigned)gy < (unsigned)Hn && (unsigned)gx < (unsigned)Wn) {
                size_t p = (size_t)b * CHW + (size_t)gy * Wn + gx;
                v0 = x[p] * sc[0] + sh[0];
                v1 = x[p + HW] * sc[1] + sh[1];
                v2 = x[p + 2 * HW] * sc[2] + sh[2];
            }
            *(uint4*)(mt8 + e * 8) = make_uint4(t2(v0, v1), (unsigned)t1(v2), 0u, 0u);
        }
    } else {
        for (int e = t; e < 20 * 21; e += 256) {
            int yy = e / 21, xx = e - yy * 21;
            float v0 = 0, v1 = 0, v2 = 0;
            if (xx < 20) {
                size_t p = (size_t)b * CHW + (size_t)(ty0 - 2 + yy) * Wn + (tx0 - 2 + xx);
                v0 = x[p] * sc[0] + sh[0];
                v1 = x[p + HW] * sc[1] + sh[1];
                v2 = x[p + 2 * HW] * sc[2] + sh[2];
            }
            *(uint4*)(mt8 + e * 8) = make_uint4(t2(v0, v1), (unsigned)t1(v2), 0u, 0u);
        }
    }
    const int wv = t >> 6, lane = t & 63, ln = lane & 15, q = lane >> 4;
    bfx8 Bf[3][3];
    #pragma unroll
    for (int ks = 0; ks < 3; ++ks)
        #pragma unroll
        for (int nt = 0; nt < 3; ++nt)
            Bf[ks][nt] = *(const bfx8*)(wh1 + (nt * 16 + ln) * 96 + ks * 32 + q * 8);
    float bph[4], bz0[4], bz1[4];
    #pragma unroll
    for (int r = 0; r < 4; ++r) {
        int ch = q * 4 + r;
        bph[r] = phb1[ch]; bz0[r] = zb1[ch]; bz1[r] = zb1[16 + ch];
    }
    __syncthreads();
    // conv1 (bf16 MFMA, swapped) -> silu -> ht8 (fp8 packed dwords, zero outside image)
    for (int mt = wv; mt < 21; mt += 4) {
        int p = mt * 16 + ln; if (p > 323) p = 323;
        const int hy = p / 18, hx = p - hy * 18;
        fx4 a0 = {0,0,0,0}, a1 = {0,0,0,0}, a2 = {0,0,0,0};
        #pragma unroll
        for (int ks = 0; ks < 3; ++ks) {
            bfx8 A = *(const bfx8*)(mt8 + ((hy + ks) * 21 + hx + q) * 8);
            a0 = __builtin_amdgcn_mfma_f32_16x16x32_bf16(Bf[ks][0], A, a0, 0, 0, 0);
            a1 = __builtin_amdgcn_mfma_f32_16x16x32_bf16(Bf[ks][1], A, a1, 0, 0, 0);
            a2 = __builtin_amdgcn_mfma_f32_16x16x32_bf16(Bf[ks][2], A, a2, 0, 0, 0);
        }
        bool live = true;
        if (edge) {
            const int gy = ty0 - 1 + hy, gx = tx0 - 1 + hx;
            live = (unsigned)gy < (unsigned)Hn && (unsigned)gx < (unsigned)Wn;
        }
        unsigned d0 = pk4f8(siluf(a0[0] + bph[0]), siluf(a0[1] + bph[1]),
                            siluf(a0[2] + bph[2]), siluf(a0[3] + bph[3]));
        unsigned d1 = pk4f8(siluf(a1[0] + bz0[0]), siluf(a1[1] + bz0[1]),
                            siluf(a1[2] + bz0[2]), siluf(a1[3] + bz0[3]));
        unsigned d2 = pk4f8(siluf(a2[0] + bz1[0]), siluf(a2[1] + bz1[1]),
                            siluf(a2[2] + bz1[2]), siluf(a2[3] + bz1[3]));
        if (!live) { d0 = 0u; d1 = 0u; d2 = 0u; }
        unsigned* hp = (unsigned*)(ht8 + p * 48 + q * 4);
        hp[0] = d0; hp[4] = d1; hp[8] = d2;
    }
    __syncthreads();
    // conv2 (SWAPPED): 9 tap-GEMMs on fp8 MFMA. Lane owns channels q*4+r at position ln.
    fx4 accp[4], accz[4];
    #pragma unroll
    for (int i = 0; i < 4; ++i) { accp[i] = fx4{0,0,0,0}; accz[i] = fx4{0,0,0,0}; }
    #pragma unroll
    for (int tap = 0; tap < 9; ++tap) {
        const int ky = tap / 3, kx = tap - ky * 3;
        long Bp = *(const long*)(wp2 + tap * 512 + ln * 32 + q * 8);
        long Bz = *(const long*)(wz2 + tap * 512 + ln * 32 + q * 8);
        #pragma unroll
        for (int i = 0; i < 4; ++i) {
            const int oy = wv * 4 + i;
            const unsigned char* ap = ht8 + ((oy + ky) * 18 + ln + kx) * 48;
            long Ap = *(const long*)(ap + q * 8);
            long Az = *(const long*)(ap + 16 + q * 8);
            accp[i] = __builtin_amdgcn_mfma_f32_16x16x32_fp8_fp8(Bp, Ap, accp[i], 0, 0, 0);
            accz[i] = __builtin_amdgcn_mfma_f32_16x16x32_fp8_fp8(Bz, Az, accz[i], 0, 0, 0);
        }
    }
    // epilogue via LDS (wave-local redistribution): full-lane tanh/sigm, coalesced fp16 stores
    __syncthreads();                       // all conv2 ht8 reads (cross-wave halo) done
    float* phs = (float*)ht8;              // [256][4]
    float* zs  = phs + 1024;               // [256][4]
    if (q == 0) {                          // channels 0..2 live in q==0 lanes (r<3)
        #pragma unroll
        for (int i = 0; i < 4; ++i) {
            int pl = (wv * 4 + i) * 16 + ln;
            #pragma unroll
            for (int r = 0; r < 3; ++r) {
                phs[pl * 4 + r] = accp[i][r];
                zs [pl * 4 + r] = accz[i][r];
            }
        }
    }
    asm volatile("" ::: "memory");         // writer px rows == reader px rows per wave
    float4 pv = ((const float4*)phs)[t];
    float4 zv = ((const float4*)zs)[t];
    const int gy = ty0 + (t >> 4), gx = tx0 + (t & 15);
    size_t pp = (size_t)b * CHW + (size_t)gy * Wn + gx;
    phi[pp]          = f2h(ftanh(pv.x + phb2[0]) * PIf);
    phi[pp + HW]     = f2h(ftanh(pv.y + phb2[1]) * PIf);
    phi[pp + 2 * HW] = f2h(ftanh(pv.z + phb2[2]) * PIf);
    float z0 = sigm(zv.x + zb2[0]) * 0.3f;
    float z1 = sigm(zv.y + zb2[1]) * 0.3f;
    float z2 = sigm(zv.z + zb2[2]) * 0.3f;
    blockReduceSum3(z0, z1, z2);
    if (t == 0) {
        part[PZ + (size_t)(b * 3 + 0) * 1024 + local] = z0;
        part[PZ + (size_t)(b * 3 + 1) * 1024 + local] = z1;
        part[PZ + (size_t)(b * 3 + 2) * 1024 + local] = z2;
    }
}

// ---------------- FFT: 512-pt Stockham radix-4 (x4) + radix-2, wave-per-line ----------------
template<bool INV>
DINL float2* fft512_wave4(float2* a, float2* b, const float2* tw, int l)
{
    float2* src = a; float2* dst = b;
    int s = 1;
    #pragma unroll
    for (int st = 0; st < 4; ++st) {
        #pragma unroll
        for (int h = 0; h < 2; ++h) {
            const int i = l + h * 64;          // butterfly index in [0,128)
            const int q = i & (s - 1);
            const int sm = i - q;              // s*m
            const int si = SW(i);              // +128/+256/+384 are swizzle-invariant
            float2 A = src[si], B = src[si + 128], C = src[si + 256], D = src[si + 384];
            float t0x = A.x + C.x, t0y = A.y + C.y;
            float t1x = A.x - C.x, t1y = A.y - C.y;
            float t2x = B.x + D.x, t2y = B.y + D.y;
            float t3x = B.x - D.x, t3y = B.y - D.y;
            float i3x = INV ? -t3y : t3y;
            float i3y = INV ? t3x : -t3x;
            float u0x = t0x + t2x, u0y = t0y + t2y;
            float u2x = t0x - t2x, u2y = t0y - t2y;
            float u1x = t1x + i3x, u1y = t1y + i3y;
            float u3x = t1x - i3x, u3y = t1y - i3y;
            float2 w1 = tw[SW(sm)], w2 = tw[SW(2 * sm)], w3 = tw[SW(3 * sm)];
            float w1y = INV ? -w1.y : w1.y;
            float w2y = INV ? -w2.y : w2.y;
            float w3y = INV ? -w3.y : w3.y;
            const int base = q + 4 * sm;
            dst[SW(base)]         = make_float2(u0x, u0y);
            dst[SW(base + s)]     = make_float2(u1x * w1.x - u1y * w1y, u1x * w1y + u1y * w1.x);
            dst[SW(base + 2 * s)] = make_float2(u2x * w2.x - u2y * w2y, u2x * w2y + u2y * w2.x);
            dst[SW(base + 3 * s)] = make_float2(u3x * w3.x - u3y * w3y, u3x * w3y + u3y * w3.x);
        }
        float2* tmp = src; src = dst; dst = tmp;
        s <<= 2;
        asm volatile("" ::: "memory");   // wave-synchronous LDS: fence compiler only
    }
    // final radix-2, s=256 (m=0 -> no twiddle)
    #pragma unroll
    for (int h = 0; h < 4; ++h) {
        const int j = l + h * 64;
        const int sj = SW(j);              // +256 swizzle-invariant
        float2 u = src[sj], v = src[sj + 256];
        dst[sj]       = make_float2(u.x + v.x, u.y + v.y);
        dst[sj + 256] = make_float2(u.x - v.x, u.y - v.y);
    }
    float2* tmp = src; src = dst; dst = tmp;
    asm volatile("" ::: "memory");
    return src;
}

__global__ __launch_bounds__(256) void k_fftA(
    const float* __restrict__ x, const unsigned short* __restrict__ phi,
    unsigned* __restrict__ U, const float2* __restrict__ gtw)
{
    __shared__ float2 buf[4][2][512];
    __shared__ float2 tw[512];
    const int t = threadIdx.x, wv = t >> 6, l = t & 63;
    #pragma unroll
    for (int i = t; i < 512; i += 256) tw[SW(i)] = gtw[i];
    __syncthreads();
    const size_t line = (size_t)blockIdx.x * 4 + wv;
    const float* xr = x + line * 512;
    const unsigned short* pr = phi + line * 512;
    float2* A = buf[wv][0];
    float2* B = buf[wv][1];
    #pragma unroll
    for (int i = l; i < 512; i += 64) {
        float s, c; __sincosf(h2f(pr[i]), &s, &c);
        float xv = xr[i];
        A[SW(i)] = make_float2(xv * c, xv * s);
    }
    asm volatile("" ::: "memory");
    float2* res = fft512_wave4<false>(A, B, tw, l);
    unsigned* Ur = U + line * 512;
    #pragma unroll
    for (int i = l; i < 512; i += 64) {
        float2 v = res[SW(i)];
        Ur[i] = pkh(v.x, v.y);
    }
}

// 64x64-tile in-place transpose; block (0, img) also reduces PZ -> red[16+img]
__global__ __launch_bounds__(256) void k_transpose(unsigned* __restrict__ U,
                                                   const float* __restrict__ part,
                                                   float* __restrict__ red)
{
    const int img = blockIdx.y;
    if (blockIdx.x == 0) {
        float4 a4 = ((const float4*)(part + PZ + (size_t)img * 1024))[threadIdx.x];
        float r = blockReduceSum(a4.x + a4.y + a4.z + a4.w);
        if (threadIdx.x == 0) red[16 + img] = r;
    }
    int rem = blockIdx.x, ti = 0;
    while (rem >= 8 - ti) { rem -= 8 - ti; ++ti; }
    const int tj = ti + rem;
    unsigned* Ub = U + (size_t)img * HW;
    __shared__ unsigned ta[64][65];
    __shared__ unsigned tb[64][65];
    const int t = threadIdx.x;
    const int cc = t & 63, r0 = t >> 6;
    const int ar = ti * 64, ac = tj * 64;
    #pragma unroll
    for (int k = 0; k < 16; ++k) {
        int r = r0 + k * 4;
        ta[r][cc] = Ub[(size_t)(ar + r) * 512 + ac + cc];
    }
    if (ti != tj) {
        #pragma unroll
        for (int k = 0; k < 16; ++k) {
            int r = r0 + k * 4;
            tb[r][cc] = Ub[(size_t)(ac + r) * 512 + ar + cc];
        }
    }
    __syncthreads();
    #pragma unroll
    for (int k = 0; k < 16; ++k) {
        int r = r0 + k * 4;
        Ub[(size_t)(ac + r) * 512 + ar + cc] = ta[cc][r];
    }
    if (ti != tj) {
        #pragma unroll
        for (int k = 0; k < 16; ++k) {
            int r = r0 + k * 4;
            Ub[(size_t)(ar + r) * 512 + ac + cc] = tb[cc][r];
        }
    }
}

__global__ __launch_bounds__(256) void k_fftB(
    unsigned* __restrict__ U, const float* __restrict__ red,
    const float* __restrict__ fgain, const float2* __restrict__ gtw)
{
    __shared__ float2 buf[4][2][512];
    __shared__ float2 tw[512];
    const int t = threadIdx.x, wv = t >> 6, l = t & 63;
    #pragma unroll
    for (int i = t; i < 512; i += 256) tw[SW(i)] = gtw[i];
    const int line = blockIdx.x * 4 + wv;          // (b*3+c)*512 + fw
    const int bc = line >> 9;
    const int fw = line & 511;
    const int c = bc % 3;
    const float zm = red[16 + bc] * (1.f / HW);
    __syncthreads();
    unsigned* Ur = U + (size_t)line * 512;
    float2* A = buf[wv][0];
    float2* B = buf[wv][1];
    #pragma unroll
    for (int i = l; i < 512; i += 64) A[SW(i)] = uph(Ur[i]);
    asm volatile("" ::: "memory");
    float2* res = fft512_wave4<false>(A, B, tw, l);
    const float gain = 1.f + fgain[c];
    const float lam  = (c == 0) ? 0.65f : (c == 1) ? 0.53f : 0.47f;
    const float il2  = 1.f / (lam * lam);
    const float fwv  = (float)(fw < 256 ? fw : fw - 512) * (1.f / 512.f);
    const float f2w  = fwv * fwv;
    #pragma unroll
    for (int i = l; i < 512; i += 64) {
        float fh = (float)(i < 256 ? i : i - 512) * (1.f / 512.f);
        float kz = 2.f * PIf * sqrtf(fmaxf(il2 - f2w - fh * fh, 0.f));
        float sn, cs; __sincosf(kz * zm, &sn, &cs);
        const int si = SW(i);
        float2 v = res[si];
        res[si] = make_float2(gain * (v.x * cs - v.y * sn), gain * (v.x * sn + v.y * cs));
    }
    asm volatile("" ::: "memory");
    float2* other = (res == A) ? B : A;
    float2* res2 = fft512_wave4<true>(res, other, tw, l);
    #pragma unroll
    for (int i = l; i < 512; i += 64) {
        float2 v = res2[SW(i)];
        Ur[i] = pkh(v.x * (1.f / 512.f), v.y * (1.f / 512.f));
    }
}

__global__ __launch_bounds__(256) void k_fftC(
    const unsigned* __restrict__ U, unsigned short* __restrict__ J,
    const float2* __restrict__ gtw)
{
    __shared__ float2 buf[4][2][512];
    __shared__ float2 tw[512];
    const int t = threadIdx.x, wv = t >> 6, l = t & 63;
    #pragma unroll
    for (int i = t; i < 512; i += 256) tw[SW(i)] = gtw[i];
    __syncthreads();
    const size_t line = (size_t)blockIdx.x * 4 + wv;
    const unsigned* Ur = U + line * 512;
    float2* A = buf[wv][0];
    float2* B = buf[wv][1];
    #pragma unroll
    for (int i = l; i < 512; i += 64) A[SW(i)] = uph(Ur[i]);
    asm volatile("" ::: "memory");
    float2* res = fft512_wave4<true>(A, B, tw, l);
    unsigned short* Jr = J + line * 512;
    #pragma unroll
    for (int i = l; i < 512; i += 64) {
        float2 v = res[SW(i)];
        float re = v.x * (1.f / 512.f), im = v.y * (1.f / 512.f);
        Jr[i] = f2h(sqrtf(fmaxf(re * re + im * im, 1e-12f)));
    }
}

// ---------------- mix path (MFMA) ----------------
// stats-only conv1 pass: 32x32 tile (no hidden halo needed), d5 folded into weights
__global__ __launch_bounds__(256) void k_m1(
    const float* __restrict__ x, const unsigned short* __restrict__ Jb,
    const unsigned short* __restrict__ w1bf, const float* __restrict__ b1,
    float* __restrict__ part)
{
    const int tx0 = blockIdx.x * 32, ty0 = blockIdx.y * 32, b = blockIdx.z;
    const int local = blockIdx.y * 16 + blockIdx.x;
    const bool edge = (blockIdx.x == 0) || (blockIdx.x == 15) ||
                      (blockIdx.y == 0) || (blockIdx.y == 15);
    __shared__ unsigned short mt8[34 * 35 * 8];
    const int t = threadIdx.x;
    for (int e = t; e < 34 * 35; e += 256) {
        int yy = e / 35, xx = e - yy * 35;
        int gy = ty0 - 1 + yy, gx = tx0 - 1 + xx;
        float v0 = 0, v1 = 0, v2 = 0, jl = 0;
        bool ok = edge ? (xx < 34 && (unsigned)gy < (unsigned)Hn && (unsigned)gx < (unsigned)Wn)
                       : (xx < 34);
        if (ok) {
            size_t p = (size_t)b * CHW + (size_t)gy * Wn + gx;
            v0 = x[p]; v1 = x[p + HW]; v2 = x[p + 2 * HW];
            jl = 0.299f * h2f(Jb[p]) + 0.587f * h2f(Jb[p + HW]) + 0.114f * h2f(Jb[p + 2 * HW]);
        }
        *(uint4*)(mt8 + e * 8) = make_uint4(t2(v0, v1), t2(v2, jl), 0u, 0u);
    }
    __syncthreads();
    const int wv = t >> 6, lane = t & 63, ln = lane & 15, q = lane >> 4;
    bfx8 Bf[3][2];
    #pragma unroll
    for (int ks = 0; ks < 3; ++ks)
        #pragma unroll
        for (int nt = 0; nt < 2; ++nt)
            Bf[ks][nt] = *(const bfx8*)(w1bf + (nt * 16 + ln) * 96 + ks * 32 + q * 8);
    const float b1v0 = b1[ln], b1v1 = b1[16 + ln];
    float s = 0.f, ss = 0.f;
    for (int g = wv; g < 64; g += 4) {      // 64 position groups: row = g>>1, coltile = g&1
        const int row = g >> 1, ct = (g & 1) * 16;
        fx4 a0 = {0.f, 0.f, 0.f, 0.f}, a1 = {0.f, 0.f, 0.f, 0.f};
        #pragma unroll
        for (int ks = 0; ks < 3; ++ks) {
            bfx8 A = *(const bfx8*)(mt8 + ((row + ks) * 35 + ct + ln + q) * 8);
            a0 = __builtin_amdgcn_mfma_f32_16x16x32_bf16(A, Bf[ks][0], a0, 0, 0, 0);
            a1 = __builtin_amdgcn_mfma_f32_16x16x32_bf16(A, Bf[ks][1], a1, 0, 0, 0);
        }
        #pragma unroll
        for (int r = 0; r < 4; ++r) {
            float u0 = a0[r] + b1v0, u1 = a1[r] + b1v1;
            s += u0 + u1; ss += u0 * u0 + u1 * u1;
        }
    }
    float rs = blockReduceSum(s);
    float rss = blockReduceSum(ss);
    if (t == 0) {
        part[PG1 + (size_t)b * 1024 + local] = rs;
        part[PG1 + (size_t)(8 + b) * 1024 + local] = rss;
    }
}

// conv1(bf16, swapped) -> gn1 -> silu -> conv2(fp8 MFMA, SWAPPED); y2 fp8 channel-last + gn2 partials
__global__ __launch_bounds__(256) void k_m2(
    const float* __restrict__ x, const unsigned short* __restrict__ Jb,
    const unsigned short* __restrict__ w1bf, const float* __restrict__ b1,
    const float* __restrict__ g1g, const float* __restrict__ g1b,
    const unsigned char* __restrict__ w2f8, const float* __restrict__ b2,
    float* __restrict__ part, unsigned char* __restrict__ y2)
{
    const int tx0 = blockIdx.x * 16, ty0 = blockIdx.y * 16, b = blockIdx.z;
    const int local = blockIdx.y * 32 + blockIdx.x;
    const bool edge = (blockIdx.x == 0) || (blockIdx.x == 31) ||
                      (blockIdx.y == 0) || (blockIdx.y == 31);
    __shared__ unsigned short mt8[20 * 21 * 8];
    __shared__ __attribute__((aligned(16))) unsigned char dt2[324 * 40];  // fp8 hidden (32ch + 8 pad)
    __shared__ float g1s[2];
    const int t = threadIdx.x;
    // folded gn1 stats (256+256 partials from k_m1)
    {
        float4 a4 = make_float4(0.f, 0.f, 0.f, 0.f), c4v = a4;
        if (t < 64) {
            a4  = ((const float4*)(part + PG1 + (size_t)b * 1024))[t];
            c4v = ((const float4*)(part + PG1 + (size_t)(8 + b) * 1024))[t];
        }
        float r0 = blockReduceSum(a4.x + a4.y + a4.z + a4.w);
        float r1 = blockReduceSum(c4v.x + c4v.y + c4v.z + c4v.w);
        if (t == 0) { g1s[0] = r0; g1s[1] = r1; }
        __syncthreads();
    }
    const float mu1 = g1s[0] * (1.f / (32.f * HW));
    const float rs1 = rsqrtf(g1s[1] * (1.f / (32.f * HW)) - mu1 * mu1 + GEPS);
    for (int e = t; e < 20 * 21; e += 256) {
        int yy = e / 21, xx = e - yy * 21;
        int gy = ty0 - 2 + yy, gx = tx0 - 2 + xx;
        float v0 = 0, v1 = 0, v2 = 0, jl = 0;
        bool ok = edge ? (xx < 20 && (unsigned)gy < (unsigned)Hn && (unsigned)gx < (unsigned)Wn)
                       : (xx < 20);
        if (ok) {
            size_t p = (size_t)b * CHW + (size_t)gy * Wn + gx;
            v0 = x[p]; v1 = x[p + HW]; v2 = x[p + 2 * HW];
            jl = 0.299f * h2f(Jb[p]) + 0.587f * h2f(Jb[p + HW]) + 0.114f * h2f(Jb[p + 2 * HW]);
        }
        *(uint4*)(mt8 + e * 8) = make_uint4(t2(v0, v1), t2(v2, jl), 0u, 0u);
    }
    const int wv = t >> 6, lane = t & 63, ln = lane & 15, q = lane >> 4;
    float scv[2][4], ofv[2][4];
    #pragma unroll
    for (int g = 0; g < 2; ++g)
        #pragma unroll
        for (int r = 0; r < 4; ++r) {
            int ch = g * 16 + q * 4 + r;
            float sg = rs1 * g1g[ch];
            scv[g][r] = sg;
            ofv[g][r] = (b1[ch] - mu1) * sg + g1b[ch];
        }
    bfx8 Bf[3][2];
    #pragma unroll
    for (int ks = 0; ks < 3; ++ks)
        #pragma unroll
        for (int nt = 0; nt < 2; ++nt)
            Bf[ks][nt] = *(const bfx8*)(w1bf + (nt * 16 + ln) * 96 + ks * 32 + q * 8);
    __syncthreads();
    for (int mt = wv; mt < 21; mt += 4) {
        int p = mt * 16 + ln; if (p > 323) p = 323;
        const int hy = p / 18, hx = p - hy * 18;
        fx4 a0 = {0.f, 0.f, 0.f, 0.f}, a1 = {0.f, 0.f, 0.f, 0.f};
        #pragma unroll
        for (int ks = 0; ks < 3; ++ks) {
            bfx8 A = *(const bfx8*)(mt8 + ((hy + ks) * 21 + hx + q) * 8);
            a0 = __builtin_amdgcn_mfma_f32_16x16x32_bf16(Bf[ks][0], A, a0, 0, 0, 0);
            a1 = __builtin_amdgcn_mfma_f32_16x16x32_bf16(Bf[ks][1], A, a1, 0, 0, 0);
        }
        bool live = true;
        if (edge) {
            const int gy = ty0 - 1 + hy, gx = tx0 - 1 + hx;
            live = (unsigned)gy < (unsigned)Hn && (unsigned)gx < (unsigned)Wn;
        }
        unsigned d0 = pk4f8(siluf(a0[0] * scv[0][0] + ofv[0][0]),
                            siluf(a0[1] * scv[0][1] + ofv[0][1]),
                            siluf(a0[2] * scv[0][2] + ofv[0][2]),
                            siluf(a0[3] * scv[0][3] + ofv[0][3]));
        unsigned d1 = pk4f8(siluf(a1[0] * scv[1][0] + ofv[1][0]),
                            siluf(a1[1] * scv[1][1] + ofv[1][1]),
                            siluf(a1[2] * scv[1][2] + ofv[1][2]),
                            siluf(a1[3] * scv[1][3] + ofv[1][3]));
        if (!live) { d0 = 0u; d1 = 0u; }
        unsigned* dp = (unsigned*)(dt2 + p * 40 + q * 4);
        dp[0] = d0; dp[4] = d1;
    }
    __syncthreads();
    // conv2 SWAPPED: lane owns out-channels nt*16 + q*4+r at position ln
    fx4 c2[4][2];
    #pragma unroll
    for (int i = 0; i < 4; ++i)
        #pragma unroll
        for (int nt = 0; nt < 2; ++nt)
            c2[i][nt] = fx4{0.f, 0.f, 0.f, 0.f};
    #pragma unroll
    for (int tap = 0; tap < 9; ++tap) {
        const int ky = tap / 3, kx = tap - ky * 3;
        long B0 = *(const long*)(w2f8 + tap * 1024 + ln * 32 + q * 8);
        long B1 = *(const long*)(w2f8 + tap * 1024 + (16 + ln) * 32 + q * 8);
        #pragma unroll
        for (int i = 0; i < 4; ++i) {
            const int oy = wv * 4 + i;
            long A = *(const long*)(dt2 + ((oy + ky) * 18 + ln + kx) * 40 + q * 8);
            c2[i][0] = __builtin_amdgcn_mfma_f32_16x16x32_fp8_fp8(B0, A, c2[i][0], 0, 0, 0);
            c2[i][1] = __builtin_amdgcn_mfma_f32_16x16x32_fp8_fp8(B1, A, c2[i][1], 0, 0, 0);
        }
    }
    float bv[2][4];
    #pragma unroll
    for (int nt = 0; nt < 2; ++nt)
        #pragma unroll
        for (int r = 0; r < 4; ++r)
            bv[nt][r] = b2[nt * 16 + q * 4 + r];
    float s = 0.f, ss = 0.f;
    const int gxo = tx0 + ln;
    #pragma unroll
    for (int i = 0; i < 4; ++i) {
        const int gy = ty0 + wv * 4 + i;
        size_t base = ((size_t)b * HW + (size_t)gy * Wn + gxo) * 32 + q * 4;
        float v0 = c2[i][0][0] + bv[0][0], v1 = c2[i][0][1] + bv[0][1];
        float v2 = c2[i][0][2] + bv[0][2], v3 = c2[i][0][3] + bv[0][3];
        float w0 = c2[i][1][0] + bv[1][0], w1 = c2[i][1][1] + bv[1][1];
        float w2 = c2[i][1][2] + bv[1][2], w3 = c2[i][1][3] + bv[1][3];
        s  += v0 + v1 + v2 + v3 + w0 + w1 + w2 + w3;
        ss += v0 * v0 + v1 * v1 + v2 * v2 + v3 * v3
            + w0 * w0 + w1 * w1 + w2 * w2 + w3 * w3;
        *(unsigned*)(y2 + base)      = pk4f8(v0, v1, v2, v3);
        *(unsigned*)(y2 + base + 16) = pk4f8(w0, w1, w2, w3);
    }
    float rsum = blockReduceSum(s);
    float rss = blockReduceSum(ss);
    if (t == 0) {
        part[PG2 + (size_t)b * 1024 + local] = rsum;
        part[PG2 + (size_t)(8 + b) * 1024 + local] = rss;
    }
}

// gn2 -> silu -> 1x1 conv via per-channel silu LUT; 8 px/thread; dl fp16; PD partials (128/group)
__global__ __launch_bounds__(256) void k_m3(
    const unsigned char* __restrict__ y2,
    const float* __restrict__ prm, const float* __restrict__ b3,
    unsigned short* __restrict__ dl, float* __restrict__ part)
{
    const int t = threadIdx.x;
    const int b = blockIdx.x >> 7;                // 128 blocks per image
    const int local = blockIdx.x & 127;
    __shared__ float g2s[2];
    __shared__ float lut[8192];                   // [32 ch][256 codes]
    {
        float4 a4 = ((const float4*)(part + PG2 + (size_t)b * 1024))[t];
        float4 c4 = ((const float4*)(part + PG2 + (size_t)(8 + b) * 1024))[t];
        float r0 = blockReduceSum(a4.x + a4.y + a4.z + a4.w);
        float r1 = blockReduceSum(c4.x + c4.y + c4.z + c4.w);
        if (t == 0) { g2s[0] = r0; g2s[1] = r1; }
        __syncthreads();
    }
    const float mu = g2s[0] * (1.f / (32.f * HW));
    const float rs = rsqrtf(g2s[1] * (1.f / (32.f * HW)) - mu * mu + GEPS);
    // build silu LUT (identical arithmetic to the per-element path)
    for (int e = t; e < 8192; e += 256) {
        int j = e >> 8;
        float v = f8f<0>((unsigned)(e & 255));
        lut[e] = siluf((v - mu) * rs * prm[j] + prm[32 + j]);
    }
    __syncthreads();
    const float bb0 = b3[0], bb1 = b3[1], bb2 = b3[2];
    float s0 = 0.f, s1 = 0.f, s2 = 0.f;
    #pragma unroll
    for (int k = 0; k < 8; ++k) {
        int idx = blockIdx.x * 2048 + k * 256 + t;    // global pixel (b*HW+pix)
        int pix = idx & (HW - 1);
        const uint4* yp = (const uint4*)(y2 + (size_t)idx * 32);
        uint4 L0 = yp[0], L1 = yp[1];
        unsigned Lw[8] = {L0.x, L0.y, L0.z, L0.w, L1.x, L1.y, L1.z, L1.w};
        float a0 = bb0, a1 = bb1, a2 = bb2;
        #pragma unroll
        for (int w = 0; w < 8; ++w) {
            unsigned u = Lw[w];
            #pragma unroll
            for (int h = 0; h < 4; ++h) {
                int j = w * 4 + h;
                int code = (int)((u >> (8 * h)) & 255u);
                float sv = lut[j * 256 + code];
                a0 += sv * prm[64 + j]; a1 += sv * prm[96 + j]; a2 += sv * prm[128 + j];
            }
        }
        size_t p = (size_t)b * CHW + pix;
        dl[p] = f2h(a0); dl[p + HW] = f2h(a1); dl[p + 2 * HW] = f2h(a2);
        s0 += a0; s1 += a1; s2 += a2;
    }
    blockReduceSum3(s0, s1, s2);
    if (t == 0) {
        part[PD + (size_t)(b * 3 + 0) * 1024 + local] = s0;
        part[PD + (size_t)(b * 3 + 1) * 1024 + local] = s1;
        part[PD + (size_t)(b * 3 + 2) * 1024 + local] = s2;
    }
}

// final: reduce 24 PD groups (128 partials each) + SE head, one block
__global__ __launch_bounds__(256) void k_fin(
    const float* __restrict__ part, float* __restrict__ red,
    const float* __restrict__ w1, const float* __restrict__ b1,
    const float* __restrict__ w2, const float* __restrict__ b2,
    const float* __restrict__ alpha)
{
    __shared__ float sm[24];
    const int t = threadIdx.x, wv = t >> 6, l = t & 63;
    for (int g = wv; g < 24; g += 4) {
        const float* p = part + PD + (size_t)g * 1024;
        float s = p[l] + p[l + 64];
        #pragma unroll
        for (int o = 32; o > 0; o >>= 1) s += __shfl_down(s, o, 64);
        if (l == 0) sm[g] = s;
    }
    __syncthreads();
    if (t < 8) {
        int b = t;
        float p0 = sm[b * 3 + 0] * (1.f / HW);
        float p1 = sm[b * 3 + 1] * (1.f / HW);
        float p2 = sm[b * 3 + 2] * (1.f / HW);
        float h[4];
        #pragma unroll
        for (int j = 0; j < 4; ++j) {
            float a = b1[j] + p0 * w1[j * 3] + p1 * w1[j * 3 + 1] + p2 * w1[j * 3 + 2];
            h[j] = siluf(a);
        }
        float al = alpha[0];
        #pragma unroll
        for (int c = 0; c < 3; ++c) {
            float a = b2[c] + h[0] * w2[c * 4] + h[1] * w2[c * 4 + 1]
                            + h[2] * w2[c * 4 + 2] + h[3] * w2[c * 4 + 3];
            red[96 + b * 3 + c] = al * sigm(a);
        }
    }
}

__global__ __launch_bounds__(256) void k_out(
    const float* __restrict__ x, const unsigned short* __restrict__ dl,
    const float* __restrict__ red, float* __restrict__ out)
{
    int i = blockIdx.x * 256 + threadIdx.x;     // float4 index
    float aw = red[96 + (i >> 16)];
    float4 xv = ((const float4*)x)[i];
    uint2 dv2 = ((const uint2*)dl)[i];          // 4 fp16
    float2 d01 = uph(dv2.x);
    float2 d23 = uph(dv2.y);
    float4 o;
    o.x = xv.x + aw * d01.x; o.y = xv.y + aw * d01.y;
    o.z = xv.z + aw * d23.x; o.w = xv.w + aw * d23.y;
    ((float4*)out)[i] = o;
}

extern "C" void kernel_launch(void* const* d_in, const int* in_sizes, int n_in,
                              void* d_out, int out_size, void* d_ws, size_t ws_size,
                              hipStream_t stream)
{
    const float* x     = (const float*)d_in[0];
    const float* ng    = (const float*)d_in[1];
    const float* nb    = (const float*)d_in[2];
    const float* ph_w1 = (const float*)d_in[3];
    const float* ph_b1 = (const float*)d_in[4];
    const float* ph_w2 = (const float*)d_in[5];
    const float* ph_b2 = (const float*)d_in[6];
    const float* z_w1  = (const float*)d_in[7];
    const float* z_b1  = (const float*)d_in[8];
    const float* z_w2  = (const float*)d_in[9];
    const float* z_b2  = (const float*)d_in[10];
    const float* fgain = (const float*)d_in[11];
    const float* mw1   = (const float*)d_in[12];
    const float* mb1   = (const float*)d_in[13];
    const float* g1g   = (const float*)d_in[14];
    const float* g1b   = (const float*)d_in[15];
    const float* mw2   = (const float*)d_in[16];
    const float* mb2   = (const float*)d_in[17];
    const float* g2g   = (const float*)d_in[18];
    const float* g2b   = (const float*)d_in[19];
    const float* mw3   = (const float*)d_in[20];
    const float* mb3   = (const float*)d_in[21];
    const float* sw1   = (const float*)d_in[22];
    const float* sb1   = (const float*)d_in[23];
    const float* sw2   = (const float*)d_in[24];
    const float* sb2   = (const float*)d_in[25];
    const float* alpha = (const float*)d_in[26];

    char* ws = (char*)d_ws;
    float*  red = (float*)(ws + OFF_RED);
    unsigned short* phi = (unsigned short*)(ws + OFF_PHI);
    unsigned* U = (unsigned*)(ws + OFF_U);
    unsigned short* Jb = (unsigned short*)(ws + OFF_J);
    unsigned short* dl = (unsigned short*)(ws + OFF_D);
    unsigned char*  y2   = (unsigned char*)(ws + OFF_Y2);
    unsigned short* w1bf = (unsigned short*)(ws + OFF_W1B);
    unsigned char*  w2f8 = (unsigned char*)(ws + OFF_W2F);
    unsigned short* wh1  = (unsigned short*)(ws + OFF_WH1);
    unsigned char*  wp2  = (unsigned char*)(ws + OFF_WP2);
    unsigned char*  wz2  = (unsigned char*)(ws + OFF_WZ2);
    float* prm  = (float*)(ws + OFF_PRM);
    float* part = (float*)(ws + OFF_PART);
    float2* gtw = (float2*)(ws + OFF_TW);
    float* out = (float*)d_out;

    hipLaunchKernelGGL(k_init, dim3(293), dim3(256), 0, stream,
                       mw1, mw2, ph_w1, z_w1, ph_w2, z_w2, g2g, g2b, mw3,
                       w1bf, w2f8, wh1, wp2, wz2, prm, gtw, x, part);
    hipLaunchKernelGGL(k_heads, dim3(32, 32, 8), dim3(256), 0, stream,
                       x, ng, nb, wh1, ph_b1, z_b1, wp2, wz2, ph_b2, z_b2, phi, part);
    hipLaunchKernelGGL(k_fftA, dim3(3072), dim3(256), 0, stream, x, phi, U, gtw);
    hipLaunchKernelGGL(k_transpose, dim3(36, 24), dim3(256), 0, stream, U, part, red);
    hipLaunchKernelGGL(k_fftB, dim3(3072), dim3(256), 0, stream, U, red, fgain, gtw);
    hipLaunchKernelGGL(k_transpose, dim3(36, 24), dim3(256), 0, stream, U, part, red);
    hipLaunchKernelGGL(k_fftC, dim3(3072), dim3(256), 0, stream, U, Jb, gtw);
    hipLaunchKernelGGL(k_m1, dim3(16, 16, 8), dim3(256), 0, stream, x, Jb, w1bf, mb1, part);
    hipLaunchKernelGGL(k_m2, dim3(32, 32, 8), dim3(256), 0, stream,
                       x, Jb, w1bf, mb1, g1g, g1b, w2f8, mb2, part, y2);
    hipLaunchKernelGGL(k_m3, dim3(1024), dim3(256), 0, stream, y2, prm, mb3, dl, part);
    hipLaunchKernelGGL(k_fin, dim3(1), dim3(256), 0, stream, part, red, sw1, sb1, sw2, sb2, alpha);
    hipLaunchKernelGGL(k_out, dim3(6144), dim3(256), 0, stream, x, dl, red, out);
}

// Round 10
// 460.989 us; speedup vs baseline: 1.0341x; 1.0341x over previous
//
#include <hip/hip_runtime.h>
#include <hip/hip_bf16.h>
#include <math.h>

#define DINL __device__ __forceinline__

namespace {
constexpr int Bn = 8, Cn = 3, Hn = 512, Wn = 512;
constexpr int HW  = Hn * Wn;        // 262144
constexpr int CHW = Cn * HW;        // 786432
constexpr float GEPS = 1e-5f;
constexpr float PIf  = 3.14159265358979323846f;

// workspace layout (bytes) — U half2, J/phi/dl fp16, y2 fp8 channel-last
constexpr size_t OFF_RED = 0;                                   // 128 floats
constexpr size_t OFF_PHI = 512;                                 // Bn*CHW ushort
constexpr size_t OFF_U   = OFF_PHI + (size_t)Bn * CHW * 2;      // Bn*CHW uint (half2)
constexpr size_t OFF_J   = OFF_U   + (size_t)Bn * CHW * 4;      // Bn*CHW ushort
constexpr size_t OFF_D   = OFF_J   + (size_t)Bn * CHW * 2;      // Bn*CHW ushort
constexpr size_t OFF_Y2  = OFF_D   + (size_t)Bn * CHW * 2;      // 8*32*HW fp8 (channel-last)
constexpr size_t OFF_W1B = OFF_Y2  + (size_t)Bn * 32 * HW;      // 3072 bf16
constexpr size_t OFF_W2F = OFF_W1B + 3072 * 2;                  // 9216 fp8 (mix conv2)
constexpr size_t OFF_WH1 = OFF_W2F + 9216;                      // 4608 bf16
constexpr size_t OFF_WP2 = OFF_WH1 + 4608 * 2;                  // 4608 fp8
constexpr size_t OFF_WZ2 = OFF_WP2 + 4608;                      // 4608 fp8
constexpr size_t OFF_PRM = OFF_WZ2 + 4608;                      // 160 f32
constexpr size_t OFF_PART= OFF_PRM + 160 * 4;                   // 81920 f32 partials
constexpr size_t OFF_TW  = OFF_PART + 81920 * 4;                // 512 float2 twiddles
// part float sub-offsets (in floats)
constexpr int PZ = 0;          // 24 groups (b*3+c) x 1024
constexpr int PG1 = 24576;     // 16 groups (b:sum, 8+b:ss) x 1024 (256 used; first 512 floats reused for x-stats)
constexpr int PG2 = 40960;     // 16 groups x 1024
constexpr int PD  = 57344;     // 24 groups (b*3+c) x 1024 (first 128 used)
}

typedef __bf16 bfx8 __attribute__((ext_vector_type(8)));
typedef float  fx4  __attribute__((ext_vector_type(4)));
typedef float  fx2  __attribute__((ext_vector_type(2)));

DINL float frcp(float a) { return __builtin_amdgcn_rcpf(a); }   // v_rcp_f32, 1 ULP
DINL float sigm(float a) { return frcp(1.f + __expf(-a)); }
DINL float siluf(float a) { return a * frcp(1.f + __expf(-a)); }
DINL float ftanh(float a) { return 1.f - 2.f * frcp(1.f + __expf(2.f * a)); }
DINL unsigned short f2bf(float f) {           // RNE float->bf16 bits
    unsigned u = __float_as_uint(f);
    return (unsigned short)((u + 0x7FFFu + ((u >> 16) & 1u)) >> 16);
}
DINL float bf2f(unsigned short h) {
    return __uint_as_float(((unsigned)h) << 16);
}
// truncating bf16 (LDS-internal MFMA operands only; 1 inst each)
DINL unsigned short t1(float a) { return (unsigned short)(__float_as_uint(a) >> 16); }
DINL unsigned t2(float a, float b) {
    return (__float_as_uint(a) >> 16) | (__float_as_uint(b) & 0xFFFF0000u);
}
// fp8 e4m3 (OCP) — saturating HW convert
DINL unsigned char f2f8(float v) {
    return (unsigned char)(__builtin_amdgcn_cvt_pk_fp8_f32(v, v, 0, false) & 0xFF);
}
DINL unsigned short pk8(float a, float b) {   // 2 fp8 in low 16 bits
    return (unsigned short)(__builtin_amdgcn_cvt_pk_fp8_f32(a, b, 0, false) & 0xFFFF);
}
DINL unsigned pk4f8(float a, float b, float c, float d) {  // 4 fp8 in a dword
    unsigned u = __builtin_amdgcn_cvt_pk_fp8_f32(a, b, 0, false);
    u = __builtin_amdgcn_cvt_pk_fp8_f32(c, d, u, true);
    return u;
}
template<int SEL>
DINL float f8f(unsigned u) { return __builtin_amdgcn_cvt_f32_fp8(u, SEL); }
// fp16 helpers
DINL unsigned pkh(float a, float b) {
    auto h = __builtin_amdgcn_cvt_pkrtz(a, b);   // __fp16 ext_vector(2)
    unsigned u; __builtin_memcpy(&u, &h, 4); return u;
}
DINL float2 uph(unsigned u) {
    _Float16 h[2]; __builtin_memcpy(h, &u, 4);
    return make_float2((float)h[0], (float)h[1]);
}
DINL unsigned short f2h(float a) {
    _Float16 h = (_Float16)a; unsigned short s; __builtin_memcpy(&s, &h, 2); return s;
}
DINL float h2f(unsigned short s) {
    _Float16 h; __builtin_memcpy(&h, &s, 2); return (float)h;
}

// LDS bank swizzle for the FFT float2 buffers: XOR bits 4-6 into bits 0-2.
DINL int SW(int e) { return e ^ ((e >> 4) & 7); }

DINL float blockReduceSum(float v) {   // blockDim.x == 256
    __shared__ float sm[4];
    int lane = threadIdx.x & 63, wid = threadIdx.x >> 6;
    #pragma unroll
    for (int o = 32; o > 0; o >>= 1) v += __shfl_down(v, o, 64);
    __syncthreads();
    if (lane == 0) sm[wid] = v;
    __syncthreads();
    if (wid == 0) {
        float r = (lane < 4) ? sm[lane] : 0.f;
        r += __shfl_down(r, 2, 64);
        r += __shfl_down(r, 1, 64);
        return r;                       // valid on thread 0
    }
    return 0.f;
}

DINL void blockReduceSum3(float& a, float& b, float& c) {   // valid on thread 0
    __shared__ float sm3[12];
    int lane = threadIdx.x & 63, wid = threadIdx.x >> 6;
    #pragma unroll
    for (int o = 32; o > 0; o >>= 1) {
        a += __shfl_down(a, o, 64);
        b += __shfl_down(b, o, 64);
        c += __shfl_down(c, o, 64);
    }
    __syncthreads();
    if (lane == 0) { sm3[wid] = a; sm3[4 + wid] = b; sm3[8 + wid] = c; }
    __syncthreads();
    if (threadIdx.x == 0) {
        a = sm3[0] + sm3[1] + sm3[2] + sm3[3];
        b = sm3[4] + sm3[5] + sm3[6] + sm3[7];
        c = sm3[8] + sm3[9] + sm3[10] + sm3[11];
    }
}

// merged: weight repack (0..35) + twiddle build (36) + x-stat partials (37..292)
// w1bf has the d5 channel FOLDED: w'_c = w_c - L_c*w_4 (c<3), w'_3 = w_3 + w_4.
__global__ __launch_bounds__(256) void k_init(
    const float* __restrict__ w1, const float* __restrict__ w2,
    const float* __restrict__ phw1, const float* __restrict__ zw1,
    const float* __restrict__ phw2, const float* __restrict__ zw2,
    const float* __restrict__ g2g, const float* __restrict__ g2b,
    const float* __restrict__ w3,
    unsigned short* __restrict__ w1bf, unsigned char* __restrict__ w2f8,
    unsigned short* __restrict__ wh1, unsigned char* __restrict__ wp2,
    unsigned char* __restrict__ wz2, float* __restrict__ prm,
    float2* __restrict__ gtw,
    const float* __restrict__ x, float* __restrict__ part)
{
    if (blockIdx.x < 36) {
        int i = blockIdx.x * 256 + threadIdx.x;     // 0..9215
        if (i < 3072) {
            int o = i / 96, k = i - o * 96;
            int ky = k >> 5, r = k & 31, kx = r >> 3, c = r & 7;
            float v = 0.f;
            if (kx < 3 && c < 4) {
                float base = w1[o * 45 + c * 9 + ky * 3 + kx];
                float w4   = w1[o * 45 + 4 * 9 + ky * 3 + kx];
                v = (c == 3) ? base + w4
                  : base - ((c == 0) ? 0.299f : (c == 1) ? 0.587f : 0.114f) * w4;
            }
            w1bf[i] = f2bf(v);
        }
        if (i < 9216) {
            int tap = i >> 10, rr = i & 1023, o = rr >> 5, ci = rr & 31;
            w2f8[i] = f2f8(w2[o * 288 + ci * 9 + tap]);
        }
        if (i < 4608) {
            int o = i / 96, k = i - o * 96;
            int ky = k >> 5, r = k & 31, kx = r >> 3, c = r & 7;
            float v = 0.f;
            if (kx < 3 && c < 3)
                v = (o < 16) ? phw1[o * 27 + c * 9 + ky * 3 + kx]
                             : zw1[(o - 16) * 27 + c * 9 + ky * 3 + kx];
            wh1[i] = f2bf(v);
        }
        if (i < 4608) {
            int tap = i / 512, rr = i - tap * 512, n = rr >> 5, k = rr & 31;
            float vp = (n < 3 && k < 16) ? phw2[n * 144 + k * 9 + tap] : 0.f;
            float vz = (n < 3) ? zw2[n * 288 + k * 9 + tap] : 0.f;
            wp2[i] = f2f8(vp);
            wz2[i] = f2f8(vz);
        }
        if (i < 160) {      // natural channel order (y2 byte j = channel j after conv2 swap)
            if (i < 32) {
                prm[i] = g2g[i];
            } else if (i < 64) {
                prm[i] = g2b[i - 32];
            } else {
                int j = (i - 64) & 31, c = (i - 64) >> 5;
                prm[i] = w3[c * 32 + j];
            }
        }
        return;
    }
    if (blockIdx.x == 36) {   // global twiddle table
        for (int i = threadIdx.x; i < 512; i += 256) {
            float s, c; __sincosf(-2.f * PIf * (float)i * (1.f / 512.f), &s, &c);
            gtw[i] = make_float2(c, s);
        }
        return;
    }
    const int bid = blockIdx.x - 37;
    const int b = bid >> 5, blk = bid & 31;
    const float4* xv = (const float4*)(x + (size_t)b * CHW + (size_t)blk * (CHW / 32));
    float s = 0.f, ss = 0.f;
    for (int i = threadIdx.x; i < (CHW / 32) / 4; i += 256) {
        float4 v = xv[i];
        s  += v.x + v.y + v.z + v.w;
        ss += v.x * v.x + v.y * v.y + v.z * v.z + v.w * v.w;
    }
    float rs = blockReduceSum(s);
    float rss = blockReduceSum(ss);
    if (threadIdx.x == 0) {
        part[PG1 + b * 64 + blk] = rs;
        part[PG1 + b * 64 + 32 + blk] = rss;
    }
}

// ---------------- fused heads (MFMA): xn -> [ph16 | z32] hidden(fp8) -> phi + z partials ----------------
// conv1 swapped (channel-major); conv2 UNswapped (position-major) — the 56-VGPR configuration
// measured fastest (R4-era); the conv2-swap variant cost +12 VGPR / -7% occupancy and regressed.
__global__ __launch_bounds__(256) void k_heads(
    const float* __restrict__ x,
    const float* __restrict__ ng, const float* __restrict__ nb,
    const unsigned short* __restrict__ wh1,
    const float* __restrict__ phb1, const float* __restrict__ zb1,
    const unsigned char* __restrict__ wp2, const unsigned char* __restrict__ wz2,
    const float* __restrict__ phb2, const float* __restrict__ zb2,
    unsigned short* __restrict__ phi, float* __restrict__ part)
{
    const int tx0 = blockIdx.x * 16, ty0 = blockIdx.y * 16, b = blockIdx.z;
    const int local = blockIdx.y * 32 + blockIdx.x;
    const bool edge = (blockIdx.x == 0) || (blockIdx.x == 31) ||
                      (blockIdx.y == 0) || (blockIdx.y == 31);
    __shared__ unsigned short mt8[20 * 21 * 8];
    __shared__ __attribute__((aligned(16))) unsigned char ht8[324 * 48];  // fp8 hidden; reused as phs/zs
    __shared__ float xst[2];
    const int t = threadIdx.x;
    // folded x-stats reduce (32+32 partials from k_init)
    {
        const float* px = part + PG1 + (size_t)b * 64;
        float sv  = (t < 32) ? px[t] : 0.f;
        float ssv = (t >= 32 && t < 64) ? px[t] : 0.f;
        float r0 = blockReduceSum(sv);
        float r1 = blockReduceSum(ssv);
        if (t == 0) { xst[0] = r0; xst[1] = r1; }
        __syncthreads();
    }
    const float mu = xst[0] * (1.f / CHW);
    const float rsv = rsqrtf(xst[1] * (1.f / CHW) - mu * mu + GEPS);
    float sc[3], sh[3];
    #pragma unroll
    for (int c = 0; c < 3; ++c) { sc[c] = rsv * ng[c]; sh[c] = nb[c] - mu * rsv * ng[c]; }
    if (edge) {
        for (int e = t; e < 20 * 21; e += 256) {
            int yy = e / 21, xx = e - yy * 21;
            int gy = ty0 - 2 + yy, gx = tx0 - 2 + xx;
            float v0 = 0, v1 = 0, v2 = 0;
            if (xx < 20 && (unsigned)gy < (unsigned)Hn && (unsigned)gx < (unsigned)Wn) {
                size_t p = (size_t)b * CHW + (size_t)gy * Wn + gx;
                v0 = x[p] * sc[0] + sh[0];
                v1 = x[p + HW] * sc[1] + sh[1];
                v2 = x[p + 2 * HW] * sc[2] + sh[2];
            }
            *(uint4*)(mt8 + e * 8) = make_uint4(t2(v0, v1), (unsigned)t1(v2), 0u, 0u);
        }
    } else {
        for (int e = t; e < 20 * 21; e += 256) {
            int yy = e / 21, xx = e - yy * 21;
            float v0 = 0, v1 = 0, v2 = 0;
            if (xx < 20) {
                size_t p = (size_t)b * CHW + (size_t)(ty0 - 2 + yy) * Wn + (tx0 - 2 + xx);
                v0 = x[p] * sc[0] + sh[0];
                v1 = x[p + HW] * sc[1] + sh[1];
                v2 = x[p + 2 * HW] * sc[2] + sh[2];
            }
            *(uint4*)(mt8 + e * 8) = make_uint4(t2(v0, v1), (unsigned)t1(v2), 0u, 0u);
        }
    }
    const int wv = t >> 6, lane = t & 63, ln = lane & 15, q = lane >> 4;
    bfx8 Bf[3][3];
    #pragma unroll
    for (int ks = 0; ks < 3; ++ks)
        #pragma unroll
        for (int nt = 0; nt < 3; ++nt)
            Bf[ks][nt] = *(const bfx8*)(wh1 + (nt * 16 + ln) * 96 + ks * 32 + q * 8);
    float bph[4], bz0[4], bz1[4];
    #pragma unroll
    for (int r = 0; r < 4; ++r) {
        int ch = q * 4 + r;
        bph[r] = phb1[ch]; bz0[r] = zb1[ch]; bz1[r] = zb1[16 + ch];
    }
    __syncthreads();
    // conv1 (bf16 MFMA, swapped) -> silu -> ht8 (fp8 packed dwords, zero outside image)
    for (int mt = wv; mt < 21; mt += 4) {
        int p = mt * 16 + ln; if (p > 323) p = 323;
        const int hy = p / 18, hx = p - hy * 18;
        fx4 a0 = {0,0,0,0}, a1 = {0,0,0,0}, a2 = {0,0,0,0};
        #pragma unroll
        for (int ks = 0; ks < 3; ++ks) {
            bfx8 A = *(const bfx8*)(mt8 + ((hy + ks) * 21 + hx + q) * 8);
            a0 = __builtin_amdgcn_mfma_f32_16x16x32_bf16(Bf[ks][0], A, a0, 0, 0, 0);
            a1 = __builtin_amdgcn_mfma_f32_16x16x32_bf16(Bf[ks][1], A, a1, 0, 0, 0);
            a2 = __builtin_amdgcn_mfma_f32_16x16x32_bf16(Bf[ks][2], A, a2, 0, 0, 0);
        }
        bool live = true;
        if (edge) {
            const int gy = ty0 - 1 + hy, gx = tx0 - 1 + hx;
            live = (unsigned)gy < (unsigned)Hn && (unsigned)gx < (unsigned)Wn;
        }
        unsigned d0 = pk4f8(siluf(a0[0] + bph[0]), siluf(a0[1] + bph[1]),
                            siluf(a0[2] + bph[2]), siluf(a0[3] + bph[3]));
        unsigned d1 = pk4f8(siluf(a1[0] + bz0[0]), siluf(a1[1] + bz0[1]),
                            siluf(a1[2] + bz0[2]), siluf(a1[3] + bz0[3]));
        unsigned d2 = pk4f8(siluf(a2[0] + bz1[0]), siluf(a2[1] + bz1[1]),
                            siluf(a2[2] + bz1[2]), siluf(a2[3] + bz1[3]));
        if (!live) { d0 = 0u; d1 = 0u; d2 = 0u; }
        unsigned* hp = (unsigned*)(ht8 + p * 48 + q * 4);
        hp[0] = d0; hp[4] = d1; hp[8] = d2;
    }
    __syncthreads();
    // conv2 (unswapped): 9 tap-GEMMs on fp8 MFMA (K=32). Lane owns 4 positions x 1 channel.
    fx4 accp[4], accz[4];
    #pragma unroll
    for (int i = 0; i < 4; ++i) { accp[i] = fx4{0,0,0,0}; accz[i] = fx4{0,0,0,0}; }
    #pragma unroll
    for (int tap = 0; tap < 9; ++tap) {
        const int ky = tap / 3, kx = tap - ky * 3;
        long Bp = *(const long*)(wp2 + tap * 512 + ln * 32 + q * 8);
        long Bz = *(const long*)(wz2 + tap * 512 + ln * 32 + q * 8);
        #pragma unroll
        for (int i = 0; i < 4; ++i) {
            const int oy = wv * 4 + i;
            const unsigned char* ap = ht8 + ((oy + ky) * 18 + ln + kx) * 48;
            long Ap = *(const long*)(ap + q * 8);
            long Az = *(const long*)(ap + 16 + q * 8);
            accp[i] = __builtin_amdgcn_mfma_f32_16x16x32_fp8_fp8(Ap, Bp, accp[i], 0, 0, 0);
            accz[i] = __builtin_amdgcn_mfma_f32_16x16x32_fp8_fp8(Az, Bz, accz[i], 0, 0, 0);
        }
    }
    // epilogue via LDS (wave-local redistribution): full-lane tanh/sigm, coalesced fp16 stores
    __syncthreads();                       // all conv2 ht8 reads (cross-wave halo) done
    float* phs = (float*)ht8;              // [256][4]
    float* zs  = phs + 1024;               // [256][4]
    if (ln < 3) {
        #pragma unroll
        for (int i = 0; i < 4; ++i)
            #pragma unroll
            for (int r = 0; r < 4; ++r) {
                int pl = (wv * 4 + i) * 16 + q * 4 + r;
                phs[pl * 4 + ln] = accp[i][r];
                zs [pl * 4 + ln] = accz[i][r];
            }
    }
    asm volatile("" ::: "memory");         // writer px rows == reader px rows per wave
    float4 pv = ((const float4*)phs)[t];
    float4 zv = ((const float4*)zs)[t];
    const int gy = ty0 + (t >> 4), gx = tx0 + (t & 15);
    size_t pp = (size_t)b * CHW + (size_t)gy * Wn + gx;
    phi[pp]          = f2h(ftanh(pv.x + phb2[0]) * PIf);
    phi[pp + HW]     = f2h(ftanh(pv.y + phb2[1]) * PIf);
    phi[pp + 2 * HW] = f2h(ftanh(pv.z + phb2[2]) * PIf);
    float z0 = sigm(zv.x + zb2[0]) * 0.3f;
    float z1 = sigm(zv.y + zb2[1]) * 0.3f;
    float z2 = sigm(zv.z + zb2[2]) * 0.3f;
    blockReduceSum3(z0, z1, z2);
    if (t == 0) {
        part[PZ + (size_t)(b * 3 + 0) * 1024 + local] = z0;
        part[PZ + (size_t)(b * 3 + 1) * 1024 + local] = z1;
        part[PZ + (size_t)(b * 3 + 2) * 1024 + local] = z2;
    }
}

// ---------------- FFT: 512-pt Stockham radix-4 (x4) + radix-2, wave-per-line ----------------
template<bool INV>
DINL float2* fft512_wave4(float2* a, float2* b, const float2* tw, int l)
{
    float2* src = a; float2* dst = b;
    int s = 1;
    #pragma unroll
    for (int st = 0; st < 4; ++st) {
        #pragma unroll
        for (int h = 0; h < 2; ++h) {
            const int i = l + h * 64;          // butterfly index in [0,128)
            const int q = i & (s - 1);
            const int sm = i - q;              // s*m
            const int si = SW(i);              // +128/+256/+384 are swizzle-invariant
            float2 A = src[si], B = src[si + 128], C = src[si + 256], D = src[si + 384];
            float t0x = A.x + C.x, t0y = A.y + C.y;
            float t1x = A.x - C.x, t1y = A.y - C.y;
            float t2x = B.x + D.x, t2y = B.y + D.y;
            float t3x = B.x - D.x, t3y = B.y - D.y;
            float i3x = INV ? -t3y : t3y;
            float i3y = INV ? t3x : -t3x;
            float u0x = t0x + t2x, u0y = t0y + t2y;
            float u2x = t0x - t2x, u2y = t0y - t2y;
            float u1x = t1x + i3x, u1y = t1y + i3y;
            float u3x = t1x - i3x, u3y = t1y - i3y;
            float2 w1 = tw[SW(sm)], w2 = tw[SW(2 * sm)], w3 = tw[SW(3 * sm)];
            float w1y = INV ? -w1.y : w1.y;
            float w2y = INV ? -w2.y : w2.y;
            float w3y = INV ? -w3.y : w3.y;
            const int base = q + 4 * sm;
            dst[SW(base)]         = make_float2(u0x, u0y);
            dst[SW(base + s)]     = make_float2(u1x * w1.x - u1y * w1y, u1x * w1y + u1y * w1.x);
            dst[SW(base + 2 * s)] = make_float2(u2x * w2.x - u2y * w2y, u2x * w2y + u2y * w2.x);
            dst[SW(base + 3 * s)] = make_float2(u3x * w3.x - u3y * w3y, u3x * w3y + u3y * w3.x);
        }
        float2* tmp = src; src = dst; dst = tmp;
        s <<= 2;
        asm volatile("" ::: "memory");   // wave-synchronous LDS: fence compiler only
    }
    // final radix-2, s=256 (m=0 -> no twiddle)
    #pragma unroll
    for (int h = 0; h < 4; ++h) {
        const int j = l + h * 64;
        const int sj = SW(j);              // +256 swizzle-invariant
        float2 u = src[sj], v = src[sj + 256];
        dst[sj]       = make_float2(u.x + v.x, u.y + v.y);
        dst[sj + 256] = make_float2(u.x - v.x, u.y - v.y);
    }
    float2* tmp = src; src = dst; dst = tmp;
    asm volatile("" ::: "memory");
    return src;
}

__global__ __launch_bounds__(256) void k_fftA(
    const float* __restrict__ x, const unsigned short* __restrict__ phi,
    unsigned* __restrict__ U, const float2* __restrict__ gtw)
{
    __shared__ float2 buf[4][2][512];
    __shared__ float2 tw[512];
    const int t = threadIdx.x, wv = t >> 6, l = t & 63;
    #pragma unroll
    for (int i = t; i < 512; i += 256) tw[SW(i)] = gtw[i];
    __syncthreads();
    const size_t line = (size_t)blockIdx.x * 4 + wv;
    const float* xr = x + line * 512;
    const unsigned short* pr = phi + line * 512;
    float2* A = buf[wv][0];
    float2* B = buf[wv][1];
    #pragma unroll
    for (int i = l; i < 512; i += 64) {
        float s, c; __sincosf(h2f(pr[i]), &s, &c);
        float xv = xr[i];
        A[SW(i)] = make_float2(xv * c, xv * s);
    }
    asm volatile("" ::: "memory");
    float2* res = fft512_wave4<false>(A, B, tw, l);
    unsigned* Ur = U + line * 512;
    #pragma unroll
    for (int i = l; i < 512; i += 64) {
        float2 v = res[SW(i)];
        Ur[i] = pkh(v.x, v.y);
    }
}

// 64x64-tile in-place transpose; block (0, img) also reduces PZ -> red[16+img]
__global__ __launch_bounds__(256) void k_transpose(unsigned* __restrict__ U,
                                                   const float* __restrict__ part,
                                                   float* __restrict__ red)
{
    const int img = blockIdx.y;
    if (blockIdx.x == 0) {
        float4 a4 = ((const float4*)(part + PZ + (size_t)img * 1024))[threadIdx.x];
        float r = blockReduceSum(a4.x + a4.y + a4.z + a4.w);
        if (threadIdx.x == 0) red[16 + img] = r;
    }
    int rem = blockIdx.x, ti = 0;
    while (rem >= 8 - ti) { rem -= 8 - ti; ++ti; }
    const int tj = ti + rem;
    unsigned* Ub = U + (size_t)img * HW;
    __shared__ unsigned ta[64][65];
    __shared__ unsigned tb[64][65];
    const int t = threadIdx.x;
    const int cc = t & 63, r0 = t >> 6;
    const int ar = ti * 64, ac = tj * 64;
    #pragma unroll
    for (int k = 0; k < 16; ++k) {
        int r = r0 + k * 4;
        ta[r][cc] = Ub[(size_t)(ar + r) * 512 + ac + cc];
    }
    if (ti != tj) {
        #pragma unroll
        for (int k = 0; k < 16; ++k) {
            int r = r0 + k * 4;
            tb[r][cc] = Ub[(size_t)(ac + r) * 512 + ar + cc];
        }
    }
    __syncthreads();
    #pragma unroll
    for (int k = 0; k < 16; ++k) {
        int r = r0 + k * 4;
        Ub[(size_t)(ac + r) * 512 + ar + cc] = ta[cc][r];
    }
    if (ti != tj) {
        #pragma unroll
        for (int k = 0; k < 16; ++k) {
            int r = r0 + k * 4;
            Ub[(size_t)(ar + r) * 512 + ac + cc] = tb[cc][r];
        }
    }
}

__global__ __launch_bounds__(256) void k_fftB(
    unsigned* __restrict__ U, const float* __restrict__ red,
    const float* __restrict__ fgain, const float2* __restrict__ gtw)
{
    __shared__ float2 buf[4][2][512];
    __shared__ float2 tw[512];
    const int t = threadIdx.x, wv = t >> 6, l = t & 63;
    #pragma unroll
    for (int i = t; i < 512; i += 256) tw[SW(i)] = gtw[i];
    const int line = blockIdx.x * 4 + wv;          // (b*3+c)*512 + fw
    const int bc = line >> 9;
    const int fw = line & 511;
    const int c = bc % 3;
    const float zm = red[16 + bc] * (1.f / HW);
    __syncthreads();
    unsigned* Ur = U + (size_t)line * 512;
    float2* A = buf[wv][0];
    float2* B = buf[wv][1];
    #pragma unroll
    for (int i = l; i < 512; i += 64) A[SW(i)] = uph(Ur[i]);
    asm volatile("" ::: "memory");
    float2* res = fft512_wave4<false>(A, B, tw, l);
    const float gain = 1.f + fgain[c];
    const float lam  = (c == 0) ? 0.65f : (c == 1) ? 0.53f : 0.47f;
    const float il2  = 1.f / (lam * lam);
    const float fwv  = (float)(fw < 256 ? fw : fw - 512) * (1.f / 512.f);
    const float f2w  = fwv * fwv;
    #pragma unroll
    for (int i = l; i < 512; i += 64) {
        float fh = (float)(i < 256 ? i : i - 512) * (1.f / 512.f);
        float kz = 2.f * PIf * sqrtf(fmaxf(il2 - f2w - fh * fh, 0.f));
        float sn, cs; __sincosf(kz * zm, &sn, &cs);
        const int si = SW(i);
        float2 v = res[si];
        res[si] = make_float2(gain * (v.x * cs - v.y * sn), gain * (v.x * sn + v.y * cs));
    }
    asm volatile("" ::: "memory");
    float2* other = (res == A) ? B : A;
    float2* res2 = fft512_wave4<true>(res, other, tw, l);
    #pragma unroll
    for (int i = l; i < 512; i += 64) {
        float2 v = res2[SW(i)];
        Ur[i] = pkh(v.x * (1.f / 512.f), v.y * (1.f / 512.f));
    }
}

__global__ __launch_bounds__(256) void k_fftC(
    const unsigned* __restrict__ U, unsigned short* __restrict__ J,
    const float2* __restrict__ gtw)
{
    __shared__ float2 buf[4][2][512];
    __shared__ float2 tw[512];
    const int t = threadIdx.x, wv = t >> 6, l = t & 63;
    #pragma unroll
    for (int i = t; i < 512; i += 256) tw[SW(i)] = gtw[i];
    __syncthreads();
    const size_t line = (size_t)blockIdx.x * 4 + wv;
    const unsigned* Ur = U + line * 512;
    float2* A = buf[wv][0];
    float2* B = buf[wv][1];
    #pragma unroll
    for (int i = l; i < 512; i += 64) A[SW(i)] = uph(Ur[i]);
    asm volatile("" ::: "memory");
    float2* res = fft512_wave4<true>(A, B, tw, l);
    unsigned short* Jr = J + line * 512;
    #pragma unroll
    for (int i = l; i < 512; i += 64) {
        float2 v = res[SW(i)];
        float re = v.x * (1.f / 512.f), im = v.y * (1.f / 512.f);
        Jr[i] = f2h(sqrtf(fmaxf(re * re + im * im, 1e-12f)));
    }
}

// ---------------- mix path (MFMA) ----------------
// stats-only conv1 pass: 32x32 tile (no hidden halo needed), d5 folded into weights
__global__ __launch_bounds__(256) void k_m1(
    const float* __restrict__ x, const unsigned short* __restrict__ Jb,
    const unsigned short* __restrict__ w1bf, const float* __restrict__ b1,
    float* __restrict__ part)
{
    const int tx0 = blockIdx.x * 32, ty0 = blockIdx.y * 32, b = blockIdx.z;
    const int local = blockIdx.y * 16 + blockIdx.x;
    const bool edge = (blockIdx.x == 0) || (blockIdx.x == 15) ||
                      (blockIdx.y == 0) || (blockIdx.y == 15);
    __shared__ unsigned short mt8[34 * 35 * 8];
    const int t = threadIdx.x;
    for (int e = t; e < 34 * 35; e += 256) {
        int yy = e / 35, xx = e - yy * 35;
        int gy = ty0 - 1 + yy, gx = tx0 - 1 + xx;
        float v0 = 0, v1 = 0, v2 = 0, jl = 0;
        bool ok = edge ? (xx < 34 && (unsigned)gy < (unsigned)Hn && (unsigned)gx < (unsigned)Wn)
                       : (xx < 34);
        if (ok) {
            size_t p = (size_t)b * CHW + (size_t)gy * Wn + gx;
            v0 = x[p]; v1 = x[p + HW]; v2 = x[p + 2 * HW];
            jl = 0.299f * h2f(Jb[p]) + 0.587f * h2f(Jb[p + HW]) + 0.114f * h2f(Jb[p + 2 * HW]);
        }
        *(uint4*)(mt8 + e * 8) = make_uint4(t2(v0, v1), t2(v2, jl), 0u, 0u);
    }
    __syncthreads();
    const int wv = t >> 6, lane = t & 63, ln = lane & 15, q = lane >> 4;
    bfx8 Bf[3][2];
    #pragma unroll
    for (int ks = 0; ks < 3; ++ks)
        #pragma unroll
        for (int nt = 0; nt < 2; ++nt)
            Bf[ks][nt] = *(const bfx8*)(w1bf + (nt * 16 + ln) * 96 + ks * 32 + q * 8);
    const float b1v0 = b1[ln], b1v1 = b1[16 + ln];
    float s = 0.f, ss = 0.f;
    for (int g = wv; g < 64; g += 4) {      // 64 position groups: row = g>>1, coltile = g&1
        const int row = g >> 1, ct = (g & 1) * 16;
        fx4 a0 = {0.f, 0.f, 0.f, 0.f}, a1 = {0.f, 0.f, 0.f, 0.f};
        #pragma unroll
        for (int ks = 0; ks < 3; ++ks) {
            bfx8 A = *(const bfx8*)(mt8 + ((row + ks) * 35 + ct + ln + q) * 8);
            a0 = __builtin_amdgcn_mfma_f32_16x16x32_bf16(A, Bf[ks][0], a0, 0, 0, 0);
            a1 = __builtin_amdgcn_mfma_f32_16x16x32_bf16(A, Bf[ks][1], a1, 0, 0, 0);
        }
        #pragma unroll
        for (int r = 0; r < 4; ++r) {
            float u0 = a0[r] + b1v0, u1 = a1[r] + b1v1;
            s += u0 + u1; ss += u0 * u0 + u1 * u1;
        }
    }
    float rs = blockReduceSum(s);
    float rss = blockReduceSum(ss);
    if (t == 0) {
        part[PG1 + (size_t)b * 1024 + local] = rs;
        part[PG1 + (size_t)(8 + b) * 1024 + local] = rss;
    }
}

// conv1(bf16, swapped) -> gn1 -> silu -> conv2(fp8 MFMA, SWAPPED); y2 fp8 channel-last + gn2 partials
__global__ __launch_bounds__(256) void k_m2(
    const float* __restrict__ x, const unsigned short* __restrict__ Jb,
    const unsigned short* __restrict__ w1bf, const float* __restrict__ b1,
    const float* __restrict__ g1g, const float* __restrict__ g1b,
    const unsigned char* __restrict__ w2f8, const float* __restrict__ b2,
    float* __restrict__ part, unsigned char* __restrict__ y2)
{
    const int tx0 = blockIdx.x * 16, ty0 = blockIdx.y * 16, b = blockIdx.z;
    const int local = blockIdx.y * 32 + blockIdx.x;
    const bool edge = (blockIdx.x == 0) || (blockIdx.x == 31) ||
                      (blockIdx.y == 0) || (blockIdx.y == 31);
    __shared__ unsigned short mt8[20 * 21 * 8];
    __shared__ __attribute__((aligned(16))) unsigned char dt2[324 * 40];  // fp8 hidden (32ch + 8 pad)
    __shared__ float g1s[2];
    const int t = threadIdx.x;
    // folded gn1 stats (256+256 partials from k_m1)
    {
        float4 a4 = make_float4(0.f, 0.f, 0.f, 0.f), c4v = a4;
        if (t < 64) {
            a4  = ((const float4*)(part + PG1 + (size_t)b * 1024))[t];
            c4v = ((const float4*)(part + PG1 + (size_t)(8 + b) * 1024))[t];
        }
        float r0 = blockReduceSum(a4.x + a4.y + a4.z + a4.w);
        float r1 = blockReduceSum(c4v.x + c4v.y + c4v.z + c4v.w);
        if (t == 0) { g1s[0] = r0; g1s[1] = r1; }
        __syncthreads();
    }
    const float mu1 = g1s[0] * (1.f / (32.f * HW));
    const float rs1 = rsqrtf(g1s[1] * (1.f / (32.f * HW)) - mu1 * mu1 + GEPS);
    for (int e = t; e < 20 * 21; e += 256) {
        int yy = e / 21, xx = e - yy * 21;
        int gy = ty0 - 2 + yy, gx = tx0 - 2 + xx;
        float v0 = 0, v1 = 0, v2 = 0, jl = 0;
        bool ok = edge ? (xx < 20 && (unsigned)gy < (unsigned)Hn && (unsigned)gx < (unsigned)Wn)
                       : (xx < 20);
        if (ok) {
            size_t p = (size_t)b * CHW + (size_t)gy * Wn + gx;
            v0 = x[p]; v1 = x[p + HW]; v2 = x[p + 2 * HW];
            jl = 0.299f * h2f(Jb[p]) + 0.587f * h2f(Jb[p + HW]) + 0.114f * h2f(Jb[p + 2 * HW]);
        }
        *(uint4*)(mt8 + e * 8) = make_uint4(t2(v0, v1), t2(v2, jl), 0u, 0u);
    }
    const int wv = t >> 6, lane = t & 63, ln = lane & 15, q = lane >> 4;
    float scv[2][4], ofv[2][4];
    #pragma unroll
    for (int g = 0; g < 2; ++g)
        #pragma unroll
        for (int r = 0; r < 4; ++r) {
            int ch = g * 16 + q * 4 + r;
            float sg = rs1 * g1g[ch];
            scv[g][r] = sg;
            ofv[g][r] = (b1[ch] - mu1) * sg + g1b[ch];
        }
    bfx8 Bf[3][2];
    #pragma unroll
    for (int ks = 0; ks < 3; ++ks)
        #pragma unroll
        for (int nt = 0; nt < 2; ++nt)
            Bf[ks][nt] = *(const bfx8*)(w1bf + (nt * 16 + ln) * 96 + ks * 32 + q * 8);
    __syncthreads();
    for (int mt = wv; mt < 21; mt += 4) {
        int p = mt * 16 + ln; if (p > 323) p = 323;
        const int hy = p / 18, hx = p - hy * 18;
        fx4 a0 = {0.f, 0.f, 0.f, 0.f}, a1 = {0.f, 0.f, 0.f, 0.f};
        #pragma unroll
        for (int ks = 0; ks < 3; ++ks) {
            bfx8 A = *(const bfx8*)(mt8 + ((hy + ks) * 21 + hx + q) * 8);
            a0 = __builtin_amdgcn_mfma_f32_16x16x32_bf16(Bf[ks][0], A, a0, 0, 0, 0);
            a1 = __builtin_amdgcn_mfma_f32_16x16x32_bf16(Bf[ks][1], A, a1, 0, 0, 0);
        }
        bool live = true;
        if (edge) {
            const int gy = ty0 - 1 + hy, gx = tx0 - 1 + hx;
            live = (unsigned)gy < (unsigned)Hn && (unsigned)gx < (unsigned)Wn;
        }
        unsigned d0 = pk4f8(siluf(a0[0] * scv[0][0] + ofv[0][0]),
                            siluf(a0[1] * scv[0][1] + ofv[0][1]),
                            siluf(a0[2] * scv[0][2] + ofv[0][2]),
                            siluf(a0[3] * scv[0][3] + ofv[0][3]));
        unsigned d1 = pk4f8(siluf(a1[0] * scv[1][0] + ofv[1][0]),
                            siluf(a1[1] * scv[1][1] + ofv[1][1]),
                            siluf(a1[2] * scv[1][2] + ofv[1][2]),
                            siluf(a1[3] * scv[1][3] + ofv[1][3]));
        if (!live) { d0 = 0u; d1 = 0u; }
        unsigned* dp = (unsigned*)(dt2 + p * 40 + q * 4);
        dp[0] = d0; dp[4] = d1;
    }
    __syncthreads();
    // conv2 SWAPPED: lane owns out-channels nt*16 + q*4+r at position ln
    fx4 c2[4][2];
    #pragma unroll
    for (int i = 0; i < 4; ++i)
        #pragma unroll
        for (int nt = 0; nt < 2; ++nt)
            c2[i][nt] = fx4{0.f, 0.f, 0.f, 0.f};
    #pragma unroll
    for (int tap = 0; tap < 9; ++tap) {
        const int ky = tap / 3, kx = tap - ky * 3;
        long B0 = *(const long*)(w2f8 + tap * 1024 + ln * 32 + q * 8);
        long B1 = *(const long*)(w2f8 + tap * 1024 + (16 + ln) * 32 + q * 8);
        #pragma unroll
        for (int i = 0; i < 4; ++i) {
            const int oy = wv * 4 + i;
            long A = *(const long*)(dt2 + ((oy + ky) * 18 + ln + kx) * 40 + q * 8);
            c2[i][0] = __builtin_amdgcn_mfma_f32_16x16x32_fp8_fp8(B0, A, c2[i][0], 0, 0, 0);
            c2[i][1] = __builtin_amdgcn_mfma_f32_16x16x32_fp8_fp8(B1, A, c2[i][1], 0, 0, 0);
        }
    }
    float bv[2][4];
    #pragma unroll
    for (int nt = 0; nt < 2; ++nt)
        #pragma unroll
        for (int r = 0; r < 4; ++r)
            bv[nt][r] = b2[nt * 16 + q * 4 + r];
    float s = 0.f, ss = 0.f;
    const int gxo = tx0 + ln;
    #pragma unroll
    for (int i = 0; i < 4; ++i) {
        const int gy = ty0 + wv * 4 + i;
        size_t base = ((size_t)b * HW + (size_t)gy * Wn + gxo) * 32 + q * 4;
        float v0 = c2[i][0][0] + bv[0][0], v1 = c2[i][0][1] + bv[0][1];
        float v2 = c2[i][0][2] + bv[0][2], v3 = c2[i][0][3] + bv[0][3];
        float w0 = c2[i][1][0] + bv[1][0], w1 = c2[i][1][1] + bv[1][1];
        float w2 = c2[i][1][2] + bv[1][2], w3 = c2[i][1][3] + bv[1][3];
        s  += v0 + v1 + v2 + v3 + w0 + w1 + w2 + w3;
        ss += v0 * v0 + v1 * v1 + v2 * v2 + v3 * v3
            + w0 * w0 + w1 * w1 + w2 * w2 + w3 * w3;
        *(unsigned*)(y2 + base)      = pk4f8(v0, v1, v2, v3);
        *(unsigned*)(y2 + base + 16) = pk4f8(w0, w1, w2, w3);
    }
    float rsum = blockReduceSum(s);
    float rss = blockReduceSum(ss);
    if (t == 0) {
        part[PG2 + (size_t)b * 1024 + local] = rsum;
        part[PG2 + (size_t)(8 + b) * 1024 + local] = rss;
    }
}

// gn2 -> silu -> 1x1 conv via per-channel silu LUT; 8 px/thread; dl fp16; PD partials (128/group)
__global__ __launch_bounds__(256) void k_m3(
    const unsigned char* __restrict__ y2,
    const float* __restrict__ prm, const float* __restrict__ b3,
    unsigned short* __restrict__ dl, float* __restrict__ part)
{
    const int t = threadIdx.x;
    const int b = blockIdx.x >> 7;                // 128 blocks per image
    const int local = blockIdx.x & 127;
    __shared__ float g2s[2];
    __shared__ float lut[8192];                   // [32 ch][256 codes]
    {
        float4 a4 = ((const float4*)(part + PG2 + (size_t)b * 1024))[t];
        float4 c4 = ((const float4*)(part + PG2 + (size_t)(8 + b) * 1024))[t];
        float r0 = blockReduceSum(a4.x + a4.y + a4.z + a4.w);
        float r1 = blockReduceSum(c4.x + c4.y + c4.z + c4.w);
        if (t == 0) { g2s[0] = r0; g2s[1] = r1; }
        __syncthreads();
    }
    const float mu = g2s[0] * (1.f / (32.f * HW));
    const float rs = rsqrtf(g2s[1] * (1.f / (32.f * HW)) - mu * mu + GEPS);
    // build silu LUT (identical arithmetic to the per-element path)
    for (int e = t; e < 8192; e += 256) {
        int j = e >> 8;
        float v = f8f<0>((unsigned)(e & 255));
        lut[e] = siluf((v - mu) * rs * prm[j] + prm[32 + j]);
    }
    __syncthreads();
    const float bb0 = b3[0], bb1 = b3[1], bb2 = b3[2];
    float s0 = 0.f, s1 = 0.f, s2 = 0.f;
    #pragma unroll
    for (int k = 0; k < 8; ++k) {
        int idx = blockIdx.x * 2048 + k * 256 + t;    // global pixel (b*HW+pix)
        int pix = idx & (HW - 1);
        const uint4* yp = (const uint4*)(y2 + (size_t)idx * 32);
        uint4 L0 = yp[0], L1 = yp[1];
        unsigned Lw[8] = {L0.x, L0.y, L0.z, L0.w, L1.x, L1.y, L1.z, L1.w};
        float a0 = bb0, a1 = bb1, a2 = bb2;
        #pragma unroll
        for (int w = 0; w < 8; ++w) {
            unsigned u = Lw[w];
            #pragma unroll
            for (int h = 0; h < 4; ++h) {
                int j = w * 4 + h;
                int code = (int)((u >> (8 * h)) & 255u);
                float sv = lut[j * 256 + code];
                a0 += sv * prm[64 + j]; a1 += sv * prm[96 + j]; a2 += sv * prm[128 + j];
            }
        }
        size_t p = (size_t)b * CHW + pix;
        dl[p] = f2h(a0); dl[p + HW] = f2h(a1); dl[p + 2 * HW] = f2h(a2);
        s0 += a0; s1 += a1; s2 += a2;
    }
    blockReduceSum3(s0, s1, s2);
    if (t == 0) {
        part[PD + (size_t)(b * 3 + 0) * 1024 + local] = s0;
        part[PD + (size_t)(b * 3 + 1) * 1024 + local] = s1;
        part[PD + (size_t)(b * 3 + 2) * 1024 + local] = s2;
    }
}

// final: reduce 24 PD groups (128 partials each) + SE head, one block
__global__ __launch_bounds__(256) void k_fin(
    const float* __restrict__ part, float* __restrict__ red,
    const float* __restrict__ w1, const float* __restrict__ b1,
    const float* __restrict__ w2, const float* __restrict__ b2,
    const float* __restrict__ alpha)
{
    __shared__ float sm[24];
    const int t = threadIdx.x, wv = t >> 6, l = t & 63;
    for (int g = wv; g < 24; g += 4) {
        const float* p = part + PD + (size_t)g * 1024;
        float s = p[l] + p[l + 64];
        #pragma unroll
        for (int o = 32; o > 0; o >>= 1) s += __shfl_down(s, o, 64);
        if (l == 0) sm[g] = s;
    }
    __syncthreads();
    if (t < 8) {
        int b = t;
        float p0 = sm[b * 3 + 0] * (1.f / HW);
        float p1 = sm[b * 3 + 1] * (1.f / HW);
        float p2 = sm[b * 3 + 2] * (1.f / HW);
        float h[4];
        #pragma unroll
        for (int j = 0; j < 4; ++j) {
            float a = b1[j] + p0 * w1[j * 3] + p1 * w1[j * 3 + 1] + p2 * w1[j * 3 + 2];
            h[j] = siluf(a);
        }
        float al = alpha[0];
        #pragma unroll
        for (int c = 0; c < 3; ++c) {
            float a = b2[c] + h[0] * w2[c * 4] + h[1] * w2[c * 4 + 1]
                            + h[2] * w2[c * 4 + 2] + h[3] * w2[c * 4 + 3];
            red[96 + b * 3 + c] = al * sigm(a);
        }
    }
}

__global__ __launch_bounds__(256) void k_out(
    const float* __restrict__ x, const unsigned short* __restrict__ dl,
    const float* __restrict__ red, float* __restrict__ out)
{
    int i = blockIdx.x * 256 + threadIdx.x;     // float4 index
    float aw = red[96 + (i >> 16)];
    float4 xv = ((const float4*)x)[i];
    uint2 dv2 = ((const uint2*)dl)[i];          // 4 fp16
    float2 d01 = uph(dv2.x);
    float2 d23 = uph(dv2.y);
    float4 o;
    o.x = xv.x + aw * d01.x; o.y = xv.y + aw * d01.y;
    o.z = xv.z + aw * d23.x; o.w = xv.w + aw * d23.y;
    ((float4*)out)[i] = o;
}

extern "C" void kernel_launch(void* const* d_in, const int* in_sizes, int n_in,
                              void* d_out, int out_size, void* d_ws, size_t ws_size,
                              hipStream_t stream)
{
    const float* x     = (const float*)d_in[0];
    const float* ng    = (const float*)d_in[1];
    const float* nb    = (const float*)d_in[2];
    const float* ph_w1 = (const float*)d_in[3];
    const float* ph_b1 = (const float*)d_in[4];
    const float* ph_w2 = (const float*)d_in[5];
    const float* ph_b2 = (const float*)d_in[6];
    const float* z_w1  = (const float*)d_in[7];
    const float* z_b1  = (const float*)d_in[8];
    const float* z_w2  = (const float*)d_in[9];
    const float* z_b2  = (const float*)d_in[10];
    const float* fgain = (const float*)d_in[11];
    const float* mw1   = (const float*)d_in[12];
    const float* mb1   = (const float*)d_in[13];
    const float* g1g   = (const float*)d_in[14];
    const float* g1b   = (const float*)d_in[15];
    const float* mw2   = (const float*)d_in[16];
    const float* mb2   = (const float*)d_in[17];
    const float* g2g   = (const float*)d_in[18];
    const float* g2b   = (const float*)d_in[19];
    const float* mw3   = (const float*)d_in[20];
    const float* mb3   = (const float*)d_in[21];
    const float* sw1   = (const float*)d_in[22];
    const float* sb1   = (const float*)d_in[23];
    const float* sw2   = (const float*)d_in[24];
    const float* sb2   = (const float*)d_in[25];
    const float* alpha = (const float*)d_in[26];

    char* ws = (char*)d_ws;
    float*  red = (float*)(ws + OFF_RED);
    unsigned short* phi = (unsigned short*)(ws + OFF_PHI);
    unsigned* U = (unsigned*)(ws + OFF_U);
    unsigned short* Jb = (unsigned short*)(ws + OFF_J);
    unsigned short* dl = (unsigned short*)(ws + OFF_D);
    unsigned char*  y2   = (unsigned char*)(ws + OFF_Y2);
    unsigned short* w1bf = (unsigned short*)(ws + OFF_W1B);
    unsigned char*  w2f8 = (unsigned char*)(ws + OFF_W2F);
    unsigned short* wh1  = (unsigned short*)(ws + OFF_WH1);
    unsigned char*  wp2  = (unsigned char*)(ws + OFF_WP2);
    unsigned char*  wz2  = (unsigned char*)(ws + OFF_WZ2);
    float* prm  = (float*)(ws + OFF_PRM);
    float* part = (float*)(ws + OFF_PART);
    float2* gtw = (float2*)(ws + OFF_TW);
    float* out = (float*)d_out;

    hipLaunchKernelGGL(k_init, dim3(293), dim3(256), 0, stream,
                       mw1, mw2, ph_w1, z_w1, ph_w2, z_w2, g2g, g2b, mw3,
                       w1bf, w2f8, wh1, wp2, wz2, prm, gtw, x, part);
    hipLaunchKernelGGL(k_heads, dim3(32, 32, 8), dim3(256), 0, stream,
                       x, ng, nb, wh1, ph_b1, z_b1, wp2, wz2, ph_b2, z_b2, phi, part);
    hipLaunchKernelGGL(k_fftA, dim3(3072), dim3(256), 0, stream, x, phi, U, gtw);
    hipLaunchKernelGGL(k_transpose, dim3(36, 24), dim3(256), 0, stream, U, part, red);
    hipLaunchKernelGGL(k_fftB, dim3(3072), dim3(256), 0, stream, U, red, fgain, gtw);
    hipLaunchKernelGGL(k_transpose, dim3(36, 24), dim3(256), 0, stream, U, part, red);
    hipLaunchKernelGGL(k_fftC, dim3(3072), dim3(256), 0, stream, U, Jb, gtw);
    hipLaunchKernelGGL(k_m1, dim3(16, 16, 8), dim3(256), 0, stream, x, Jb, w1bf, mb1, part);
    hipLaunchKernelGGL(k_m2, dim3(32, 32, 8), dim3(256), 0, stream,
                       x, Jb, w1bf, mb1, g1g, g1b, w2f8, mb2, part, y2);
    hipLaunchKernelGGL(k_m3, dim3(1024), dim3(256), 0, stream, y2, prm, mb3, dl, part);
    hipLaunchKernelGGL(k_fin, dim3(1), dim3(256), 0, stream, part, red, sw1, sb1, sw2, sb2, alpha);
    hipLaunchKernelGGL(k_out, dim3(6144), dim3(256), 0, stream, x, dl, red, out);
}

// Round 12
// 449.223 us; speedup vs baseline: 1.0612x; 1.0262x over previous
//
#include <hip/hip_runtime.h>
#include <hip/hip_bf16.h>
#include <math.h>

#define DINL __device__ __forceinline__

namespace {
constexpr int Bn = 8, Cn = 3, Hn = 512, Wn = 512;
constexpr int HW  = Hn * Wn;        // 262144
constexpr int CHW = Cn * HW;        // 786432
constexpr float GEPS = 1e-5f;
constexpr float PIf  = 3.14159265358979323846f;

// workspace layout (bytes) — U half2, J/phi/dl fp16, y2 fp8 channel-last
constexpr size_t OFF_RED = 0;                                   // 128 floats
constexpr size_t OFF_PHI = 512;                                 // Bn*CHW ushort
constexpr size_t OFF_U   = OFF_PHI + (size_t)Bn * CHW * 2;      // Bn*CHW uint (half2)
constexpr size_t OFF_J   = OFF_U   + (size_t)Bn * CHW * 4;      // Bn*CHW ushort
constexpr size_t OFF_D   = OFF_J   + (size_t)Bn * CHW * 2;      // Bn*CHW ushort
constexpr size_t OFF_Y2  = OFF_D   + (size_t)Bn * CHW * 2;      // 8*32*HW fp8 (channel-last)
constexpr size_t OFF_W1B = OFF_Y2  + (size_t)Bn * 32 * HW;      // 3072 bf16
constexpr size_t OFF_W2F = OFF_W1B + 3072 * 2;                  // 9216 fp8 (mix conv2)
constexpr size_t OFF_WH1 = OFF_W2F + 9216;                      // 4608 bf16
constexpr size_t OFF_WP2 = OFF_WH1 + 4608 * 2;                  // 4608 fp8
constexpr size_t OFF_WZ2 = OFF_WP2 + 4608;                      // 4608 fp8
constexpr size_t OFF_PRM = OFF_WZ2 + 4608;                      // 160 f32
constexpr size_t OFF_PART= OFF_PRM + 160 * 4;                   // 81920 f32 partials
constexpr size_t OFF_TW  = OFF_PART + 81920 * 4;                // 512 float2 twiddles
// part float sub-offsets (in floats)
constexpr int PZ = 0;          // 24 groups (b*3+c) x 1024
constexpr int PG1 = 24576;     // 16 groups (b:sum, 8+b:ss) x 1024 (256 used; first 512 floats reused for x-stats)
constexpr int PG2 = 40960;     // 16 groups x 1024
constexpr int PD  = 57344;     // 24 groups (b*3+c) x 1024 (first 128 used)
}

typedef __bf16 bfx8 __attribute__((ext_vector_type(8)));
typedef float  fx4  __attribute__((ext_vector_type(4)));
typedef float  fx2  __attribute__((ext_vector_type(2)));

DINL float frcp(float a) { return __builtin_amdgcn_rcpf(a); }   // v_rcp_f32, 1 ULP
DINL float sigm(float a) { return frcp(1.f + __expf(-a)); }
DINL float siluf(float a) { return a * frcp(1.f + __expf(-a)); }
DINL float ftanh(float a) { return 1.f - 2.f * frcp(1.f + __expf(2.f * a)); }
DINL unsigned short f2bf(float f) {           // RNE float->bf16 bits
    unsigned u = __float_as_uint(f);
    return (unsigned short)((u + 0x7FFFu + ((u >> 16) & 1u)) >> 16);
}
DINL float bf2f(unsigned short h) {
    return __uint_as_float(((unsigned)h) << 16);
}
// truncating bf16 (LDS-internal MFMA operands only; 1 inst each)
DINL unsigned short t1(float a) { return (unsigned short)(__float_as_uint(a) >> 16); }
DINL unsigned t2(float a, float b) {
    return (__float_as_uint(a) >> 16) | (__float_as_uint(b) & 0xFFFF0000u);
}
// fp8 e4m3 (OCP) — saturating HW convert
DINL unsigned char f2f8(float v) {
    return (unsigned char)(__builtin_amdgcn_cvt_pk_fp8_f32(v, v, 0, false) & 0xFF);
}
DINL unsigned short pk8(float a, float b) {   // 2 fp8 in low 16 bits
    return (unsigned short)(__builtin_amdgcn_cvt_pk_fp8_f32(a, b, 0, false) & 0xFFFF);
}
DINL unsigned pk4f8(float a, float b, float c, float d) {  // 4 fp8 in a dword
    unsigned u = __builtin_amdgcn_cvt_pk_fp8_f32(a, b, 0, false);
    u = __builtin_amdgcn_cvt_pk_fp8_f32(c, d, u, true);
    return u;
}
template<int SEL>
DINL float f8f(unsigned u) { return __builtin_amdgcn_cvt_f32_fp8(u, SEL); }
// fp16 helpers
DINL unsigned pkh(float a, float b) {
    auto h = __builtin_amdgcn_cvt_pkrtz(a, b);   // __fp16 ext_vector(2)
    unsigned u; __builtin_memcpy(&u, &h, 4); return u;
}
DINL float2 uph(unsigned u) {
    _Float16 h[2]; __builtin_memcpy(h, &u, 4);
    return make_float2((float)h[0], (float)h[1]);
}
DINL unsigned short f2h(float a) {
    _Float16 h = (_Float16)a; unsigned short s; __builtin_memcpy(&s, &h, 2); return s;
}
DINL float h2f(unsigned short s) {
    _Float16 h; __builtin_memcpy(&h, &s, 2); return (float)h;
}

// LDS bank swizzle for the FFT float2 buffers: XOR bits 4-6 into bits 0-2.
DINL int SW(int e) { return e ^ ((e >> 4) & 7); }

DINL float blockReduceSum(float v) {   // blockDim.x == 256
    __shared__ float sm[4];
    int lane = threadIdx.x & 63, wid = threadIdx.x >> 6;
    #pragma unroll
    for (int o = 32; o > 0; o >>= 1) v += __shfl_down(v, o, 64);
    __syncthreads();
    if (lane == 0) sm[wid] = v;
    __syncthreads();
    if (wid == 0) {
        float r = (lane < 4) ? sm[lane] : 0.f;
        r += __shfl_down(r, 2, 64);
        r += __shfl_down(r, 1, 64);
        return r;                       // valid on thread 0
    }
    return 0.f;
}

DINL void blockReduceSum3(float& a, float& b, float& c) {   // valid on thread 0
    __shared__ float sm3[12];
    int lane = threadIdx.x & 63, wid = threadIdx.x >> 6;
    #pragma unroll
    for (int o = 32; o > 0; o >>= 1) {
        a += __shfl_down(a, o, 64);
        b += __shfl_down(b, o, 64);
        c += __shfl_down(c, o, 64);
    }
    __syncthreads();
    if (lane == 0) { sm3[wid] = a; sm3[4 + wid] = b; sm3[8 + wid] = c; }
    __syncthreads();
    if (threadIdx.x == 0) {
        a = sm3[0] + sm3[1] + sm3[2] + sm3[3];
        b = sm3[4] + sm3[5] + sm3[6] + sm3[7];
        c = sm3[8] + sm3[9] + sm3[10] + sm3[11];
    }
}

// merged: weight repack (0..35) + twiddle build (36) + x-stat partials (37..292)
// w1bf has the d5 channel FOLDED: w'_c = w_c - L_c*w_4 (c<3), w'_3 = w_3 + w_4.
// w2f8 N-index n -> channel (n>>2)*8 + tile*4 + (n&3): lane (ln,q) owns ch q*8..q*8+7,
// so the y2 store is one contiguous 8B per lane (full-cache-line writes, no write-allocate).
__global__ __launch_bounds__(256) void k_init(
    const float* __restrict__ w1, const float* __restrict__ w2,
    const float* __restrict__ phw1, const float* __restrict__ zw1,
    const float* __restrict__ phw2, const float* __restrict__ zw2,
    const float* __restrict__ g2g, const float* __restrict__ g2b,
    const float* __restrict__ w3,
    unsigned short* __restrict__ w1bf, unsigned char* __restrict__ w2f8,
    unsigned short* __restrict__ wh1, unsigned char* __restrict__ wp2,
    unsigned char* __restrict__ wz2, float* __restrict__ prm,
    float2* __restrict__ gtw,
    const float* __restrict__ x, float* __restrict__ part)
{
    if (blockIdx.x < 36) {
        int i = blockIdx.x * 256 + threadIdx.x;     // 0..9215
        if (i < 3072) {
            int o = i / 96, k = i - o * 96;
            int ky = k >> 5, r = k & 31, kx = r >> 3, c = r & 7;
            float v = 0.f;
            if (kx < 3 && c < 4) {
                float base = w1[o * 45 + c * 9 + ky * 3 + kx];
                float w4   = w1[o * 45 + 4 * 9 + ky * 3 + kx];
                v = (c == 3) ? base + w4
                  : base - ((c == 0) ? 0.299f : (c == 1) ? 0.587f : 0.114f) * w4;
            }
            w1bf[i] = f2bf(v);
        }
        if (i < 9216) {
            int tap = i >> 10, rr = i & 1023, row = rr >> 5, ci = rr & 31;
            int n = row & 15, hi = row >> 4;
            int ch = (n >> 2) * 8 + hi * 4 + (n & 3);
            w2f8[i] = f2f8(w2[ch * 288 + ci * 9 + tap]);
        }
        if (i < 4608) {
            int o = i / 96, k = i - o * 96;
            int ky = k >> 5, r = k & 31, kx = r >> 3, c = r & 7;
            float v = 0.f;
            if (kx < 3 && c < 3)
                v = (o < 16) ? phw1[o * 27 + c * 9 + ky * 3 + kx]
                             : zw1[(o - 16) * 27 + c * 9 + ky * 3 + kx];
            wh1[i] = f2bf(v);
        }
        if (i < 4608) {
            int tap = i / 512, rr = i - tap * 512, n = rr >> 5, k = rr & 31;
            float vp = (n < 3 && k < 16) ? phw2[n * 144 + k * 9 + tap] : 0.f;
            float vz = (n < 3) ? zw2[n * 288 + k * 9 + tap] : 0.f;
            wp2[i] = f2f8(vp);
            wz2[i] = f2f8(vz);
        }
        if (i < 160) {      // natural channel order (y2 byte j = channel j)
            if (i < 32) {
                prm[i] = g2g[i];
            } else if (i < 64) {
                prm[i] = g2b[i - 32];
            } else {
                int j = (i - 64) & 31, c = (i - 64) >> 5;
                prm[i] = w3[c * 32 + j];
            }
        }
        return;
    }
    if (blockIdx.x == 36) {   // global twiddle table
        for (int i = threadIdx.x; i < 512; i += 256) {
            float s, c; __sincosf(-2.f * PIf * (float)i * (1.f / 512.f), &s, &c);
            gtw[i] = make_float2(c, s);
        }
        return;
    }
    const int bid = blockIdx.x - 37;
    const int b = bid >> 5, blk = bid & 31;
    const float4* xv = (const float4*)(x + (size_t)b * CHW + (size_t)blk * (CHW / 32));
    float s = 0.f, ss = 0.f;
    for (int i = threadIdx.x; i < (CHW / 32) / 4; i += 256) {
        float4 v = xv[i];
        s  += v.x + v.y + v.z + v.w;
        ss += v.x * v.x + v.y * v.y + v.z * v.z + v.w * v.w;
    }
    float rs = blockReduceSum(s);
    float rss = blockReduceSum(ss);
    if (threadIdx.x == 0) {
        part[PG1 + b * 64 + blk] = rs;
        part[PG1 + b * 64 + 32 + blk] = rss;
    }
}

// ---------------- fused heads (MFMA): xn -> [ph16 | z32] hidden(fp8) -> phi + z partials ----------------
// conv1 swapped (channel-major); conv2 UNswapped (position-major) — the 56-VGPR configuration.
__global__ __launch_bounds__(256) void k_heads(
    const float* __restrict__ x,
    const float* __restrict__ ng, const float* __restrict__ nb,
    const unsigned short* __restrict__ wh1,
    const float* __restrict__ phb1, const float* __restrict__ zb1,
    const unsigned char* __restrict__ wp2, const unsigned char* __restrict__ wz2,
    const float* __restrict__ phb2, const float* __restrict__ zb2,
    unsigned short* __restrict__ phi, float* __restrict__ part)
{
    const int tx0 = blockIdx.x * 16, ty0 = blockIdx.y * 16, b = blockIdx.z;
    const int local = blockIdx.y * 32 + blockIdx.x;
    const bool edge = (blockIdx.x == 0) || (blockIdx.x == 31) ||
                      (blockIdx.y == 0) || (blockIdx.y == 31);
    __shared__ unsigned short mt8[20 * 21 * 8];
    __shared__ __attribute__((aligned(16))) unsigned char ht8[324 * 48];  // fp8 hidden; reused as phs/zs
    __shared__ float xst[2];
    const int t = threadIdx.x;
    // folded x-stats reduce (32+32 partials from k_init)
    {
        const float* px = part + PG1 + (size_t)b * 64;
        float sv  = (t < 32) ? px[t] : 0.f;
        float ssv = (t >= 32 && t < 64) ? px[t] : 0.f;
        float r0 = blockReduceSum(sv);
        float r1 = blockReduceSum(ssv);
        if (t == 0) { xst[0] = r0; xst[1] = r1; }
        __syncthreads();
    }
    const float mu = xst[0] * (1.f / CHW);
    const float rsv = rsqrtf(xst[1] * (1.f / CHW) - mu * mu + GEPS);
    float sc[3], sh[3];
    #pragma unroll
    for (int c = 0; c < 3; ++c) { sc[c] = rsv * ng[c]; sh[c] = nb[c] - mu * rsv * ng[c]; }
    if (edge) {
        for (int e = t; e < 20 * 21; e += 256) {
            int yy = e / 21, xx = e - yy * 21;
            int gy = ty0 - 2 + yy, gx = tx0 - 2 + xx;
            float v0 = 0, v1 = 0, v2 = 0;
            if (xx < 20 && (unsigned)gy < (unsigned)Hn && (unsigned)gx < (unsigned)Wn) {
                size_t p = (size_t)b * CHW + (size_t)gy * Wn + gx;
                v0 = x[p] * sc[0] + sh[0];
                v1 = x[p + HW] * sc[1] + sh[1];
                v2 = x[p + 2 * HW] * sc[2] + sh[2];
            }
            *(uint4*)(mt8 + e * 8) = make_uint4(t2(v0, v1), (unsigned)t1(v2), 0u, 0u);
        }
    } else {
        for (int e = t; e < 20 * 21; e += 256) {
            int yy = e / 21, xx = e - yy * 21;
            float v0 = 0, v1 = 0, v2 = 0;
            if (xx < 20) {
                size_t p = (size_t)b * CHW + (size_t)(ty0 - 2 + yy) * Wn + (tx0 - 2 + xx);
                v0 = x[p] * sc[0] + sh[0];
                v1 = x[p + HW] * sc[1] + sh[1];
                v2 = x[p + 2 * HW] * sc[2] + sh[2];
            }
            *(uint4*)(mt8 + e * 8) = make_uint4(t2(v0, v1), (unsigned)t1(v2), 0u, 0u);
        }
    }
    const int wv = t >> 6, lane = t & 63, ln = lane & 15, q = lane >> 4;
    bfx8 Bf[3][3];
    #pragma unroll
    for (int ks = 0; ks < 3; ++ks)
        #pragma unroll
        for (int nt = 0; nt < 3; ++nt)
            Bf[ks][nt] = *(const bfx8*)(wh1 + (nt * 16 + ln) * 96 + ks * 32 + q * 8);
    float bph[4], bz0[4], bz1[4];
    #pragma unroll
    for (int r = 0; r < 4; ++r) {
        int ch = q * 4 + r;
        bph[r] = phb1[ch]; bz0[r] = zb1[ch]; bz1[r] = zb1[16 + ch];
    }
    __syncthreads();
    // conv1 (bf16 MFMA, swapped) -> silu -> ht8 (fp8 packed dwords, zero outside image)
    for (int mt = wv; mt < 21; mt += 4) {
        int p = mt * 16 + ln; if (p > 323) p = 323;
        const int hy = p / 18, hx = p - hy * 18;
        fx4 a0 = {0,0,0,0}, a1 = {0,0,0,0}, a2 = {0,0,0,0};
        #pragma unroll
        for (int ks = 0; ks < 3; ++ks) {
            bfx8 A = *(const bfx8*)(mt8 + ((hy + ks) * 21 + hx + q) * 8);
            a0 = __builtin_amdgcn_mfma_f32_16x16x32_bf16(Bf[ks][0], A, a0, 0, 0, 0);
            a1 = __builtin_amdgcn_mfma_f32_16x16x32_bf16(Bf[ks][1], A, a1, 0, 0, 0);
            a2 = __builtin_amdgcn_mfma_f32_16x16x32_bf16(Bf[ks][2], A, a2, 0, 0, 0);
        }
        bool live = true;
        if (edge) {
            const int gy = ty0 - 1 + hy, gx = tx0 - 1 + hx;
            live = (unsigned)gy < (unsigned)Hn && (unsigned)gx < (unsigned)Wn;
        }
        unsigned d0 = pk4f8(siluf(a0[0] + bph[0]), siluf(a0[1] + bph[1]),
                            siluf(a0[2] + bph[2]), siluf(a0[3] + bph[3]));
        unsigned d1 = pk4f8(siluf(a1[0] + bz0[0]), siluf(a1[1] + bz0[1]),
                            siluf(a1[2] + bz0[2]), siluf(a1[3] + bz0[3]));
        unsigned d2 = pk4f8(siluf(a2[0] + bz1[0]), siluf(a2[1] + bz1[1]),
                            siluf(a2[2] + bz1[2]), siluf(a2[3] + bz1[3]));
        if (!live) { d0 = 0u; d1 = 0u; d2 = 0u; }
        unsigned* hp = (unsigned*)(ht8 + p * 48 + q * 4);
        hp[0] = d0; hp[4] = d1; hp[8] = d2;
    }
    __syncthreads();
    // conv2 (unswapped): 9 tap-GEMMs on fp8 MFMA (K=32). Lane owns 4 positions x 1 channel.
    fx4 accp[4], accz[4];
    #pragma unroll
    for (int i = 0; i < 4; ++i) { accp[i] = fx4{0,0,0,0}; accz[i] = fx4{0,0,0,0}; }
    #pragma unroll
    for (int tap = 0; tap < 9; ++tap) {
        const int ky = tap / 3, kx = tap - ky * 3;
        long Bp = *(const long*)(wp2 + tap * 512 + ln * 32 + q * 8);
        long Bz = *(const long*)(wz2 + tap * 512 + ln * 32 + q * 8);
        #pragma unroll
        for (int i = 0; i < 4; ++i) {
            const int oy = wv * 4 + i;
            const unsigned char* ap = ht8 + ((oy + ky) * 18 + ln + kx) * 48;
            long Ap = *(const long*)(ap + q * 8);
            long Az = *(const long*)(ap + 16 + q * 8);
            accp[i] = __builtin_amdgcn_mfma_f32_16x16x32_fp8_fp8(Ap, Bp, accp[i], 0, 0, 0);
            accz[i] = __builtin_amdgcn_mfma_f32_16x16x32_fp8_fp8(Az, Bz, accz[i], 0, 0, 0);
        }
    }
    // epilogue via LDS (wave-local redistribution): full-lane tanh/sigm, coalesced fp16 stores
    __syncthreads();                       // all conv2 ht8 reads (cross-wave halo) done
    float* phs = (float*)ht8;              // [256][4]
    float* zs  = phs + 1024;               // [256][4]
    if (ln < 3) {
        #pragma unroll
        for (int i = 0; i < 4; ++i)
            #pragma unroll
            for (int r = 0; r < 4; ++r) {
                int pl = (wv * 4 + i) * 16 + q * 4 + r;
                phs[pl * 4 + ln] = accp[i][r];
                zs [pl * 4 + ln] = accz[i][r];
            }
    }
    asm volatile("" ::: "memory");         // writer px rows == reader px rows per wave
    float4 pv = ((const float4*)phs)[t];
    float4 zv = ((const float4*)zs)[t];
    const int gy = ty0 + (t >> 4), gx = tx0 + (t & 15);
    size_t pp = (size_t)b * CHW + (size_t)gy * Wn + gx;
    phi[pp]          = f2h(ftanh(pv.x + phb2[0]) * PIf);
    phi[pp + HW]     = f2h(ftanh(pv.y + phb2[1]) * PIf);
    phi[pp + 2 * HW] = f2h(ftanh(pv.z + phb2[2]) * PIf);
    float z0 = sigm(zv.x + zb2[0]) * 0.3f;
    float z1 = sigm(zv.y + zb2[1]) * 0.3f;
    float z2 = sigm(zv.z + zb2[2]) * 0.3f;
    blockReduceSum3(z0, z1, z2);
    if (t == 0) {
        part[PZ + (size_t)(b * 3 + 0) * 1024 + local] = z0;
        part[PZ + (size_t)(b * 3 + 1) * 1024 + local] = z1;
        part[PZ + (size_t)(b * 3 + 2) * 1024 + local] = z2;
    }
}

// ---------------- FFT: 512-pt Stockham radix-4 (x4) + radix-2, wave-per-line ----------------
template<bool INV>
DINL float2* fft512_wave4(float2* a, float2* b, const float2* tw, int l)
{
    float2* src = a; float2* dst = b;
    int s = 1;
    #pragma unroll
    for (int st = 0; st < 4; ++st) {
        #pragma unroll
        for (int h = 0; h < 2; ++h) {
            const int i = l + h * 64;          // butterfly index in [0,128)
            const int q = i & (s - 1);
            const int sm = i - q;              // s*m
            const int si = SW(i);              // +128/+256/+384 are swizzle-invariant
            float2 A = src[si], B = src[si + 128], C = src[si + 256], D = src[si + 384];
            float t0x = A.x + C.x, t0y = A.y + C.y;
            float t1x = A.x - C.x, t1y = A.y - C.y;
            float t2x = B.x + D.x, t2y = B.y + D.y;
            float t3x = B.x - D.x, t3y = B.y - D.y;
            float i3x = INV ? -t3y : t3y;
            float i3y = INV ? t3x : -t3x;
            float u0x = t0x + t2x, u0y = t0y + t2y;
            float u2x = t0x - t2x, u2y = t0y - t2y;
            float u1x = t1x + i3x, u1y = t1y + i3y;
            float u3x = t1x - i3x, u3y = t1y - i3y;
            float2 w1 = tw[SW(sm)], w2 = tw[SW(2 * sm)], w3 = tw[SW(3 * sm)];
            float w1y = INV ? -w1.y : w1.y;
            float w2y = INV ? -w2.y : w2.y;
            float w3y = INV ? -w3.y : w3.y;
            const int base = q + 4 * sm;
            dst[SW(base)]         = make_float2(u0x, u0y);
            dst[SW(base + s)]     = make_float2(u1x * w1.x - u1y * w1y, u1x * w1y + u1y * w1.x);
            dst[SW(base + 2 * s)] = make_float2(u2x * w2.x - u2y * w2y, u2x * w2y + u2y * w2.x);
            dst[SW(base + 3 * s)] = make_float2(u3x * w3.x - u3y * w3y, u3x * w3y + u3y * w3.x);
        }
        float2* tmp = src; src = dst; dst = tmp;
        s <<= 2;
        asm volatile("" ::: "memory");   // wave-synchronous LDS: fence compiler only
    }
    // final radix-2, s=256 (m=0 -> no twiddle)
    #pragma unroll
    for (int h = 0; h < 4; ++h) {
        const int j = l + h * 64;
        const int sj = SW(j);              // +256 swizzle-invariant
        float2 u = src[sj], v = src[sj + 256];
        dst[sj]       = make_float2(u.x + v.x, u.y + v.y);
        dst[sj + 256] = make_float2(u.x - v.x, u.y - v.y);
    }
    float2* tmp = src; src = dst; dst = tmp;
    asm volatile("" ::: "memory");
    return src;
}

__global__ __launch_bounds__(256) void k_fftA(
    const float* __restrict__ x, const unsigned short* __restrict__ phi,
    unsigned* __restrict__ U, const float2* __restrict__ gtw)
{
    __shared__ float2 buf[4][2][512];
    __shared__ float2 tw[512];
    const int t = threadIdx.x, wv = t >> 6, l = t & 63;
    #pragma unroll
    for (int i = t; i < 512; i += 256) tw[SW(i)] = gtw[i];
    __syncthreads();
    const size_t line = (size_t)blockIdx.x * 4 + wv;
    const float* xr = x + line * 512;
    const unsigned short* pr = phi + line * 512;
    float2* A = buf[wv][0];
    float2* B = buf[wv][1];
    #pragma unroll
    for (int i = l; i < 512; i += 64) {
        float s, c; __sincosf(h2f(pr[i]), &s, &c);
        float xv = xr[i];
        A[SW(i)] = make_float2(xv * c, xv * s);
    }
    asm volatile("" ::: "memory");
    float2* res = fft512_wave4<false>(A, B, tw, l);
    unsigned* Ur = U + line * 512;
    #pragma unroll
    for (int i = l; i < 512; i += 64) {
        float2 v = res[SW(i)];
        Ur[i] = pkh(v.x, v.y);
    }
}

// 64x64-tile in-place transpose; block (0, img) also reduces PZ -> red[16+img]
__global__ __launch_bounds__(256) void k_transpose(unsigned* __restrict__ U,
                                                   const float* __restrict__ part,
                                                   float* __restrict__ red)
{
    const int img = blockIdx.y;
    if (blockIdx.x == 0) {
        float4 a4 = ((const float4*)(part + PZ + (size_t)img * 1024))[threadIdx.x];
        float r = blockReduceSum(a4.x + a4.y + a4.z + a4.w);
        if (threadIdx.x == 0) red[16 + img] = r;
    }
    int rem = blockIdx.x, ti = 0;
    while (rem >= 8 - ti) { rem -= 8 - ti; ++ti; }
    const int tj = ti + rem;
    unsigned* Ub = U + (size_t)img * HW;
    __shared__ unsigned ta[64][65];
    __shared__ unsigned tb[64][65];
    const int t = threadIdx.x;
    const int cc = t & 63, r0 = t >> 6;
    const int ar = ti * 64, ac = tj * 64;
    #pragma unroll
    for (int k = 0; k < 16; ++k) {
        int r = r0 + k * 4;
        ta[r][cc] = Ub[(size_t)(ar + r) * 512 + ac + cc];
    }
    if (ti != tj) {
        #pragma unroll
        for (int k = 0; k < 16; ++k) {
            int r = r0 + k * 4;
            tb[r][cc] = Ub[(size_t)(ac + r) * 512 + ar + cc];
        }
    }
    __syncthreads();
    #pragma unroll
    for (int k = 0; k < 16; ++k) {
        int r = r0 + k * 4;
        Ub[(size_t)(ac + r) * 512 + ar + cc] = ta[cc][r];
    }
    if (ti != tj) {
        #pragma unroll
        for (int k = 0; k < 16; ++k) {
            int r = r0 + k * 4;
            Ub[(size_t)(ar + r) * 512 + ac + cc] = tb[cc][r];
        }
    }
}

__global__ __launch_bounds__(256) void k_fftB(
    unsigned* __restrict__ U, const float* __restrict__ red,
    const float* __restrict__ fgain, const float2* __restrict__ gtw)
{
    __shared__ float2 buf[4][2][512];
    __shared__ float2 tw[512];
    const int t = threadIdx.x, wv = t >> 6, l = t & 63;
    #pragma unroll
    for (int i = t; i < 512; i += 256) tw[SW(i)] = gtw[i];
    const int line = blockIdx.x * 4 + wv;          // (b*3+c)*512 + fw
    const int bc = line >> 9;
    const int fw = line & 511;
    const int c = bc % 3;
    const float zm = red[16 + bc] * (1.f / HW);
    __syncthreads();
    unsigned* Ur = U + (size_t)line * 512;
    float2* A = buf[wv][0];
    float2* B = buf[wv][1];
    #pragma unroll
    for (int i = l; i < 512; i += 64) A[SW(i)] = uph(Ur[i]);
    asm volatile("" ::: "memory");
    float2* res = fft512_wave4<false>(A, B, tw, l);
    const float gain = 1.f + fgain[c];
    const float lam  = (c == 0) ? 0.65f : (c == 1) ? 0.53f : 0.47f;
    const float il2  = 1.f / (lam * lam);
    const float fwv  = (float)(fw < 256 ? fw : fw - 512) * (1.f / 512.f);
    const float f2w  = fwv * fwv;
    #pragma unroll
    for (int i = l; i < 512; i += 64) {
        float fh = (float)(i < 256 ? i : i - 512) * (1.f / 512.f);
        float kz = 2.f * PIf * sqrtf(fmaxf(il2 - f2w - fh * fh, 0.f));
        float sn, cs; __sincosf(kz * zm, &sn, &cs);
        const int si = SW(i);
        float2 v = res[si];
        res[si] = make_float2(gain * (v.x * cs - v.y * sn), gain * (v.x * sn + v.y * cs));
    }
    asm volatile("" ::: "memory");
    float2* other = (res == A) ? B : A;
    float2* res2 = fft512_wave4<true>(res, other, tw, l);
    #pragma unroll
    for (int i = l; i < 512; i += 64) {
        float2 v = res2[SW(i)];
        Ur[i] = pkh(v.x * (1.f / 512.f), v.y * (1.f / 512.f));
    }
}

__global__ __launch_bounds__(256) void k_fftC(
    const unsigned* __restrict__ U, unsigned short* __restrict__ J,
    const float2* __restrict__ gtw)
{
    __shared__ float2 buf[4][2][512];
    __shared__ float2 tw[512];
    const int t = threadIdx.x, wv = t >> 6, l = t & 63;
    #pragma unroll
    for (int i = t; i < 512; i += 256) tw[SW(i)] = gtw[i];
    __syncthreads();
    const size_t line = (size_t)blockIdx.x * 4 + wv;
    const unsigned* Ur = U + line * 512;
    float2* A = buf[wv][0];
    float2* B = buf[wv][1];
    #pragma unroll
    for (int i = l; i < 512; i += 64) A[SW(i)] = uph(Ur[i]);
    asm volatile("" ::: "memory");
    float2* res = fft512_wave4<true>(A, B, tw, l);
    unsigned short* Jr = J + line * 512;
    #pragma unroll
    for (int i = l; i < 512; i += 64) {
        float2 v = res[SW(i)];
        float re = v.x * (1.f / 512.f), im = v.y * (1.f / 512.f);
        Jr[i] = f2h(sqrtf(fmaxf(re * re + im * im, 1e-12f)));
    }
}

// ---------------- mix path (MFMA) ----------------
// stats-only conv1 pass: 32x32 tile (no hidden halo needed), d5 folded into weights
__global__ __launch_bounds__(256) void k_m1(
    const float* __restrict__ x, const unsigned short* __restrict__ Jb,
    const unsigned short* __restrict__ w1bf, const float* __restrict__ b1,
    float* __restrict__ part)
{
    const int tx0 = blockIdx.x * 32, ty0 = blockIdx.y * 32, b = blockIdx.z;
    const int local = blockIdx.y * 16 + blockIdx.x;
    const bool edge = (blockIdx.x == 0) || (blockIdx.x == 15) ||
                      (blockIdx.y == 0) || (blockIdx.y == 15);
    __shared__ unsigned short mt8[34 * 35 * 8];
    const int t = threadIdx.x;
    for (int e = t; e < 34 * 35; e += 256) {
        int yy = e / 35, xx = e - yy * 35;
        int gy = ty0 - 1 + yy, gx = tx0 - 1 + xx;
        float v0 = 0, v1 = 0, v2 = 0, jl = 0;
        bool ok = edge ? (xx < 34 && (unsigned)gy < (unsigned)Hn && (unsigned)gx < (unsigned)Wn)
                       : (xx < 34);
        if (ok) {
            size_t p = (size_t)b * CHW + (size_t)gy * Wn + gx;
            v0 = x[p]; v1 = x[p + HW]; v2 = x[p + 2 * HW];
            jl = 0.299f * h2f(Jb[p]) + 0.587f * h2f(Jb[p + HW]) + 0.114f * h2f(Jb[p + 2 * HW]);
        }
        *(uint4*)(mt8 + e * 8) = make_uint4(t2(v0, v1), t2(v2, jl), 0u, 0u);
    }
    __syncthreads();
    const int wv = t >> 6, lane = t & 63, ln = lane & 15, q = lane >> 4;
    bfx8 Bf[3][2];
    #pragma unroll
    for (int ks = 0; ks < 3; ++ks)
        #pragma unroll
        for (int nt = 0; nt < 2; ++nt)
            Bf[ks][nt] = *(const bfx8*)(w1bf + (nt * 16 + ln) * 96 + ks * 32 + q * 8);
    const float b1v0 = b1[ln], b1v1 = b1[16 + ln];
    float s = 0.f, ss = 0.f;
    for (int g = wv; g < 64; g += 4) {      // 64 position groups: row = g>>1, coltile = g&1
        const int row = g >> 1, ct = (g & 1) * 16;
        fx4 a0 = {0.f, 0.f, 0.f, 0.f}, a1 = {0.f, 0.f, 0.f, 0.f};
        #pragma unroll
        for (int ks = 0; ks < 3; ++ks) {
            bfx8 A = *(const bfx8*)(mt8 + ((row + ks) * 35 + ct + ln + q) * 8);
            a0 = __builtin_amdgcn_mfma_f32_16x16x32_bf16(A, Bf[ks][0], a0, 0, 0, 0);
            a1 = __builtin_amdgcn_mfma_f32_16x16x32_bf16(A, Bf[ks][1], a1, 0, 0, 0);
        }
        #pragma unroll
        for (int r = 0; r < 4; ++r) {
            float u0 = a0[r] + b1v0, u1 = a1[r] + b1v1;
            s += u0 + u1; ss += u0 * u0 + u1 * u1;
        }
    }
    float rs = blockReduceSum(s);
    float rss = blockReduceSum(ss);
    if (t == 0) {
        part[PG1 + (size_t)b * 1024 + local] = rs;
        part[PG1 + (size_t)(8 + b) * 1024 + local] = rss;
    }
}

// conv1(bf16, swapped) -> gn1 -> silu -> conv2(fp8 MFMA, SWAPPED); y2 fp8 channel-last + gn2 partials
// lane (ln,q) owns channels q*8..q*8+7 -> one contiguous 8B y2 store (full-line writes)
__global__ __launch_bounds__(256) void k_m2(
    const float* __restrict__ x, const unsigned short* __restrict__ Jb,
    const unsigned short* __restrict__ w1bf, const float* __restrict__ b1,
    const float* __restrict__ g1g, const float* __restrict__ g1b,
    const unsigned char* __restrict__ w2f8, const float* __restrict__ b2,
    float* __restrict__ part, unsigned char* __restrict__ y2)
{
    const int tx0 = blockIdx.x * 16, ty0 = blockIdx.y * 16, b = blockIdx.z;
    const int local = blockIdx.y * 32 + blockIdx.x;
    const bool edge = (blockIdx.x == 0) || (blockIdx.x == 31) ||
                      (blockIdx.y == 0) || (blockIdx.y == 31);
    __shared__ unsigned short mt8[20 * 21 * 8];
    __shared__ __attribute__((aligned(16))) unsigned char dt2[324 * 40];  // fp8 hidden (32ch + 8 pad)
    __shared__ float g1s[2];
    const int t = threadIdx.x;
    // folded gn1 stats (256+256 partials from k_m1)
    {
        float4 a4 = make_float4(0.f, 0.f, 0.f, 0.f), c4v = a4;
        if (t < 64) {
            a4  = ((const float4*)(part + PG1 + (size_t)b * 1024))[t];
            c4v = ((const float4*)(part + PG1 + (size_t)(8 + b) * 1024))[t];
        }
        float r0 = blockReduceSum(a4.x + a4.y + a4.z + a4.w);
        float r1 = blockReduceSum(c4v.x + c4v.y + c4v.z + c4v.w);
        if (t == 0) { g1s[0] = r0; g1s[1] = r1; }
        __syncthreads();
    }
    const float mu1 = g1s[0] * (1.f / (32.f * HW));
    const float rs1 = rsqrtf(g1s[1] * (1.f / (32.f * HW)) - mu1 * mu1 + GEPS);
    for (int e = t; e < 20 * 21; e += 256) {
        int yy = e / 21, xx = e - yy * 21;
        int gy = ty0 - 2 + yy, gx = tx0 - 2 + xx;
        float v0 = 0, v1 = 0, v2 = 0, jl = 0;
        bool ok = edge ? (xx < 20 && (unsigned)gy < (unsigned)Hn && (unsigned)gx < (unsigned)Wn)
                       : (xx < 20);
        if (ok) {
            size_t p = (size_t)b * CHW + (size_t)gy * Wn + gx;
            v0 = x[p]; v1 = x[p + HW]; v2 = x[p + 2 * HW];
            jl = 0.299f * h2f(Jb[p]) + 0.587f * h2f(Jb[p + HW]) + 0.114f * h2f(Jb[p + 2 * HW]);
        }
        *(uint4*)(mt8 + e * 8) = make_uint4(t2(v0, v1), t2(v2, jl), 0u, 0u);
    }
    const int wv = t >> 6, lane = t & 63, ln = lane & 15, q = lane >> 4;
    float scv[2][4], ofv[2][4];
    #pragma unroll
    for (int g = 0; g < 2; ++g)
        #pragma unroll
        for (int r = 0; r < 4; ++r) {
            int ch = g * 16 + q * 4 + r;
            float sg = rs1 * g1g[ch];
            scv[g][r] = sg;
            ofv[g][r] = (b1[ch] - mu1) * sg + g1b[ch];
        }
    bfx8 Bf[3][2];
    #pragma unroll
    for (int ks = 0; ks < 3; ++ks)
        #pragma unroll
        for (int nt = 0; nt < 2; ++nt)
            Bf[ks][nt] = *(const bfx8*)(w1bf + (nt * 16 + ln) * 96 + ks * 32 + q * 8);
    __syncthreads();
    for (int mt = wv; mt < 21; mt += 4) {
        int p = mt * 16 + ln; if (p > 323) p = 323;
        const int hy = p / 18, hx = p - hy * 18;
        fx4 a0 = {0.f, 0.f, 0.f, 0.f}, a1 = {0.f, 0.f, 0.f, 0.f};
        #pragma unroll
        for (int ks = 0; ks < 3; ++ks) {
            bfx8 A = *(const bfx8*)(mt8 + ((hy + ks) * 21 + hx + q) * 8);
            a0 = __builtin_amdgcn_mfma_f32_16x16x32_bf16(Bf[ks][0], A, a0, 0, 0, 0);
            a1 = __builtin_amdgcn_mfma_f32_16x16x32_bf16(Bf[ks][1], A, a1, 0, 0, 0);
        }
        bool live = true;
        if (edge) {
            const int gy = ty0 - 1 + hy, gx = tx0 - 1 + hx;
            live = (unsigned)gy < (unsigned)Hn && (unsigned)gx < (unsigned)Wn;
        }
        unsigned d0 = pk4f8(siluf(a0[0] * scv[0][0] + ofv[0][0]),
                            siluf(a0[1] * scv[0][1] + ofv[0][1]),
                            siluf(a0[2] * scv[0][2] + ofv[0][2]),
                            siluf(a0[3] * scv[0][3] + ofv[0][3]));
        unsigned d1 = pk4f8(siluf(a1[0] * scv[1][0] + ofv[1][0]),
                            siluf(a1[1] * scv[1][1] + ofv[1][1]),
                            siluf(a1[2] * scv[1][2] + ofv[1][2]),
                            siluf(a1[3] * scv[1][3] + ofv[1][3]));
        if (!live) { d0 = 0u; d1 = 0u; }
        unsigned* dp = (unsigned*)(dt2 + p * 40 + q * 4);
        dp[0] = d0; dp[4] = d1;
    }
    __syncthreads();
    // conv2 SWAPPED: lane owns out-N-index q*4+r per tile; tile0 -> ch q*8+r, tile1 -> ch q*8+4+r
    fx4 c2[4][2];
    #pragma unroll
    for (int i = 0; i < 4; ++i)
        #pragma unroll
        for (int nt = 0; nt < 2; ++nt)
            c2[i][nt] = fx4{0.f, 0.f, 0.f, 0.f};
    #pragma unroll
    for (int tap = 0; tap < 9; ++tap) {
        const int ky = tap / 3, kx = tap - ky * 3;
        long B0 = *(const long*)(w2f8 + tap * 1024 + ln * 32 + q * 8);
        long B1 = *(const long*)(w2f8 + tap * 1024 + (16 + ln) * 32 + q * 8);
        #pragma unroll
        for (int i = 0; i < 4; ++i) {
            const int oy = wv * 4 + i;
            long A = *(const long*)(dt2 + ((oy + ky) * 18 + ln + kx) * 40 + q * 8);
            c2[i][0] = __builtin_amdgcn_mfma_f32_16x16x32_fp8_fp8(B0, A, c2[i][0], 0, 0, 0);
            c2[i][1] = __builtin_amdgcn_mfma_f32_16x16x32_fp8_fp8(B1, A, c2[i][1], 0, 0, 0);
        }
    }
    float bv[2][4];
    #pragma unroll
    for (int nt = 0; nt < 2; ++nt)
        #pragma unroll
        for (int r = 0; r < 4; ++r)
            bv[nt][r] = b2[q * 8 + nt * 4 + r];
    float s = 0.f, ss = 0.f;
    const int gxo = tx0 + ln;
    #pragma unroll
    for (int i = 0; i < 4; ++i) {
        const int gy = ty0 + wv * 4 + i;
        size_t base = ((size_t)b * HW + (size_t)gy * Wn + gxo) * 32 + q * 8;
        float v0 = c2[i][0][0] + bv[0][0], v1 = c2[i][0][1] + bv[0][1];
        float v2 = c2[i][0][2] + bv[0][2], v3 = c2[i][0][3] + bv[0][3];
        float w0 = c2[i][1][0] + bv[1][0], w1 = c2[i][1][1] + bv[1][1];
        float w2 = c2[i][1][2] + bv[1][2], w3 = c2[i][1][3] + bv[1][3];
        s  += v0 + v1 + v2 + v3 + w0 + w1 + w2 + w3;
        ss += v0 * v0 + v1 * v1 + v2 * v2 + v3 * v3
            + w0 * w0 + w1 * w1 + w2 * w2 + w3 * w3;
        unsigned lo = pk4f8(v0, v1, v2, v3);       // ch q*8..q*8+3
        unsigned hi = pk4f8(w0, w1, w2, w3);       // ch q*8+4..q*8+7
        unsigned long long pk = (unsigned long long)lo | ((unsigned long long)hi << 32);
        *(unsigned long long*)(y2 + base) = pk;    // one contiguous 8B store
    }
    float rsum = blockReduceSum(s);
    float rss = blockReduceSum(ss);
    if (t == 0) {
        part[PG2 + (size_t)b * 1024 + local] = rsum;
        part[PG2 + (size_t)(8 + b) * 1024 + local] = rss;
    }
}

// gn2 -> silu -> 1x1 conv via per-channel silu LUT; 8 px/thread; dl fp16; PD partials (128/group)
__global__ __launch_bounds__(256) void k_m3(
    const unsigned char* __restrict__ y2,
    const float* __restrict__ prm, const float* __restrict__ b3,
    unsigned short* __restrict__ dl, float* __restrict__ part)
{
    const int t = threadIdx.x;
    const int b = blockIdx.x >> 7;                // 128 blocks per image
    const int local = blockIdx.x & 127;
    __shared__ float g2s[2];
    __shared__ float lut[8192];                   // [32 ch][256 codes]
    {
        float4 a4 = ((const float4*)(part + PG2 + (size_t)b * 1024))[t];
        float4 c4 = ((const float4*)(part + PG2 + (size_t)(8 + b) * 1024))[t];
        float r0 = blockReduceSum(a4.x + a4.y + a4.z + a4.w);
        float r1 = blockReduceSum(c4.x + c4.y + c4.z + c4.w);
        if (t == 0) { g2s[0] = r0; g2s[1] = r1; }
        __syncthreads();
    }
    const float mu = g2s[0] * (1.f / (32.f * HW));
    const float rs = rsqrtf(g2s[1] * (1.f / (32.f * HW)) - mu * mu + GEPS);
    // build silu LUT (identical arithmetic to the per-element path)
    for (int e = t; e < 8192; e += 256) {
        int j = e >> 8;
        float v = f8f<0>((unsigned)(e & 255));
        lut[e] = siluf((v - mu) * rs * prm[j] + prm[32 + j]);
    }
    __syncthreads();
    const float bb0 = b3[0], bb1 = b3[1], bb2 = b3[2];
    float s0 = 0.f, s1 = 0.f, s2 = 0.f;
    #pragma unroll
    for (int k = 0; k < 8; ++k) {
        int idx = blockIdx.x * 2048 + k * 256 + t;    // global pixel (b*HW+pix)
        int pix = idx & (HW - 1);
        const uint4* yp = (const uint4*)(y2 + (size_t)idx * 32);
        uint4 L0 = yp[0], L1 = yp[1];
        unsigned Lw[8] = {L0.x, L0.y, L0.z, L0.w, L1.x, L1.y, L1.z, L1.w};
        float a0 = bb0, a1 = bb1, a2 = bb2;
        #pragma unroll
        for (int w = 0; w < 8; ++w) {
            unsigned u = Lw[w];
            #pragma unroll
            for (int h = 0; h < 4; ++h) {
                int j = w * 4 + h;
                int code = (int)((u >> (8 * h)) & 255u);
                float sv = lut[j * 256 + code];
                a0 += sv * prm[64 + j]; a1 += sv * prm[96 + j]; a2 += sv * prm[128 + j];
            }
        }
        size_t p = (size_t)b * CHW + pix;
        dl[p] = f2h(a0); dl[p + HW] = f2h(a1); dl[p + 2 * HW] = f2h(a2);
        s0 += a0; s1 += a1; s2 += a2;
    }
    blockReduceSum3(s0, s1, s2);
    if (t == 0) {
        part[PD + (size_t)(b * 3 + 0) * 1024 + local] = s0;
        part[PD + (size_t)(b * 3 + 1) * 1024 + local] = s1;
        part[PD + (size_t)(b * 3 + 2) * 1024 + local] = s2;
    }
}

// final: reduce 24 PD groups (128 partials each) + SE head, one block
__global__ __launch_bounds__(256) void k_fin(
    const float* __restrict__ part, float* __restrict__ red,
    const float* __restrict__ w1, const float* __restrict__ b1,
    const float* __restrict__ w2, const float* __restrict__ b2,
    const float* __restrict__ alpha)
{
    __shared__ float sm[24];
    const int t = threadIdx.x, wv = t >> 6, l = t & 63;
    for (int g = wv; g < 24; g += 4) {
        const float* p = part + PD + (size_t)g * 1024;
        float s = p[l] + p[l + 64];
        #pragma unroll
        for (int o = 32; o > 0; o >>= 1) s += __shfl_down(s, o, 64);
        if (l == 0) sm[g] = s;
    }
    __syncthreads();
    if (t < 8) {
        int b = t;
        float p0 = sm[b * 3 + 0] * (1.f / HW);
        float p1 = sm[b * 3 + 1] * (1.f / HW);
        float p2 = sm[b * 3 + 2] * (1.f / HW);
        float h[4];
        #pragma unroll
        for (int j = 0; j < 4; ++j) {
            float a = b1[j] + p0 * w1[j * 3] + p1 * w1[j * 3 + 1] + p2 * w1[j * 3 + 2];
            h[j] = siluf(a);
        }
        float al = alpha[0];
        #pragma unroll
        for (int c = 0; c < 3; ++c) {
            float a = b2[c] + h[0] * w2[c * 4] + h[1] * w2[c * 4 + 1]
                            + h[2] * w2[c * 4 + 2] + h[3] * w2[c * 4 + 3];
            red[96 + b * 3 + c] = al * sigm(a);
        }
    }
}

__global__ __launch_bounds__(256) void k_out(
    const float* __restrict__ x, const unsigned short* __restrict__ dl,
    const float* __restrict__ red, float* __restrict__ out)
{
    int i = blockIdx.x * 256 + threadIdx.x;     // float4 index
    float aw = red[96 + (i >> 16)];
    float4 xv = ((const float4*)x)[i];
    uint2 dv2 = ((const uint2*)dl)[i];          // 4 fp16
    float2 d01 = uph(dv2.x);
    float2 d23 = uph(dv2.y);
    float4 o;
    o.x = xv.x + aw * d01.x; o.y = xv.y + aw * d01.y;
    o.z = xv.z + aw * d23.x; o.w = xv.w + aw * d23.y;
    ((float4*)out)[i] = o;
}

extern "C" void kernel_launch(void* const* d_in, const int* in_sizes, int n_in,
                              void* d_out, int out_size, void* d_ws, size_t ws_size,
                              hipStream_t stream)
{
    const float* x     = (const float*)d_in[0];
    const float* ng    = (const float*)d_in[1];
    const float* nb    = (const float*)d_in[2];
    const float* ph_w1 = (const float*)d_in[3];
    const float* ph_b1 = (const float*)d_in[4];
    const float* ph_w2 = (const float*)d_in[5];
    const float* ph_b2 = (const float*)d_in[6];
    const float* z_w1  = (const float*)d_in[7];
    const float* z_b1  = (const float*)d_in[8];
    const float* z_w2  = (const float*)d_in[9];
    const float* z_b2  = (const float*)d_in[10];
    const float* fgain = (const float*)d_in[11];
    const float* mw1   = (const float*)d_in[12];
    const float* mb1   = (const float*)d_in[13];
    const float* g1g   = (const float*)d_in[14];
    const float* g1b   = (const float*)d_in[15];
    const float* mw2   = (const float*)d_in[16];
    const float* mb2   = (const float*)d_in[17];
    const float* g2g   = (const float*)d_in[18];
    const float* g2b   = (const float*)d_in[19];
    const float* mw3   = (const float*)d_in[20];
    const float* mb3   = (const float*)d_in[21];
    const float* sw1   = (const float*)d_in[22];
    const float* sb1   = (const float*)d_in[23];
    const float* sw2   = (const float*)d_in[24];
    const float* sb2   = (const float*)d_in[25];
    const float* alpha = (const float*)d_in[26];

    char* ws = (char*)d_ws;
    float*  red = (float*)(ws + OFF_RED);
    unsigned short* phi = (unsigned short*)(ws + OFF_PHI);
    unsigned* U = (unsigned*)(ws + OFF_U);
    unsigned short* Jb = (unsigned short*)(ws + OFF_J);
    unsigned short* dl = (unsigned short*)(ws + OFF_D);
    unsigned char*  y2   = (unsigned char*)(ws + OFF_Y2);
    unsigned short* w1bf = (unsigned short*)(ws + OFF_W1B);
    unsigned char*  w2f8 = (unsigned char*)(ws + OFF_W2F);
    unsigned short* wh1  = (unsigned short*)(ws + OFF_WH1);
    unsigned char*  wp2  = (unsigned char*)(ws + OFF_WP2);
    unsigned char*  wz2  = (unsigned char*)(ws + OFF_WZ2);
    float* prm  = (float*)(ws + OFF_PRM);
    float* part = (float*)(ws + OFF_PART);
    float2* gtw = (float2*)(ws + OFF_TW);
    float* out = (float*)d_out;

    hipLaunchKernelGGL(k_init, dim3(293), dim3(256), 0, stream,
                       mw1, mw2, ph_w1, z_w1, ph_w2, z_w2, g2g, g2b, mw3,
                       w1bf, w2f8, wh1, wp2, wz2, prm, gtw, x, part);
    hipLaunchKernelGGL(k_heads, dim3(32, 32, 8), dim3(256), 0, stream,
                       x, ng, nb, wh1, ph_b1, z_b1, wp2, wz2, ph_b2, z_b2, phi, part);
    hipLaunchKernelGGL(k_fftA, dim3(3072), dim3(256), 0, stream, x, phi, U, gtw);
    hipLaunchKernelGGL(k_transpose, dim3(36, 24), dim3(256), 0, stream, U, part, red);
    hipLaunchKernelGGL(k_fftB, dim3(3072), dim3(256), 0, stream, U, red, fgain, gtw);
    hipLaunchKernelGGL(k_transpose, dim3(36, 24), dim3(256), 0, stream, U, part, red);
    hipLaunchKernelGGL(k_fftC, dim3(3072), dim3(256), 0, stream, U, Jb, gtw);
    hipLaunchKernelGGL(k_m1, dim3(16, 16, 8), dim3(256), 0, stream, x, Jb, w1bf, mb1, part);
    hipLaunchKernelGGL(k_m2, dim3(32, 32, 8), dim3(256), 0, stream,
                       x, Jb, w1bf, mb1, g1g, g1b, w2f8, mb2, part, y2);
    hipLaunchKernelGGL(k_m3, dim3(1024), dim3(256), 0, stream, y2, prm, mb3, dl, part);
    hipLaunchKernelGGL(k_fin, dim3(1), dim3(256), 0, stream, part, red, sw1, sb1, sw2, sb2, alpha);
    hipLaunchKernelGGL(k_out, dim3(6144), dim3(256), 0, stream, x, dl, red, out);
}